// Round 1
// baseline (2754.254 us; speedup 1.0000x reference)
//
#include <hip/hip_runtime.h>
#include <cstddef>

#define NN 50000
#define NE 640000
#define HD 128
#define NG 512
#define NL 2
constexpr float BN_EPS = 1e-5f;

// ---------------------------------------------------------------------------
// GEMM: C[n x 128] = f(A) @ W[128x128] + bias
// MODE 0: f(A) = A
// MODE 1: f(A) = A + A2          (h + agg)
// MODE 2: f(A) = relu(A*scale[k] + shift[k])   (fused BN+ReLU on input)
// 512 threads, 64-row tile, each thread computes 4 rows x 4 cols.
// ---------------------------------------------------------------------------
template <int MODE>
__global__ __launch_bounds__(512) void gemm128(
    const float* __restrict__ A, const float* __restrict__ A2,
    const float* __restrict__ scale, const float* __restrict__ shift,
    const float* __restrict__ W, const float* __restrict__ bias,
    float* __restrict__ C, int n) {
  __shared__ float Wl[128 * 128];
  __shared__ float Al[64 * 132];
  const int t = threadIdx.x;
  const int row0 = blockIdx.x * 64;

  // stage W (16384 floats = 4096 float4)
  for (int i = t; i < 4096; i += 512) {
    ((float4*)Wl)[i] = ((const float4*)W)[i];
  }
  // stage A tile (64 x 128 = 2048 float4), transformed
  for (int i = t; i < 2048; i += 512) {
    const int r = i >> 5;
    const int q = i & 31;
    const int gr = row0 + r;
    float4 v;
    if (gr < n) {
      v = ((const float4*)A)[(size_t)gr * 32 + q];
      if (MODE == 1) {
        float4 u = ((const float4*)A2)[(size_t)gr * 32 + q];
        v.x += u.x; v.y += u.y; v.z += u.z; v.w += u.w;
      } else if (MODE == 2) {
        const int c = q * 4;
        v.x = fmaxf(fmaf(v.x, scale[c + 0], shift[c + 0]), 0.f);
        v.y = fmaxf(fmaf(v.y, scale[c + 1], shift[c + 1]), 0.f);
        v.z = fmaxf(fmaf(v.z, scale[c + 2], shift[c + 2]), 0.f);
        v.w = fmaxf(fmaf(v.w, scale[c + 3], shift[c + 3]), 0.f);
      }
    } else {
      v = make_float4(0.f, 0.f, 0.f, 0.f);
    }
    *(float4*)&Al[r * 132 + q * 4] = v;
  }
  __syncthreads();

  const int cg = t & 31;   // col group: cols 4cg..4cg+3
  const int rg = t >> 5;   // row group: rows 4rg..4rg+3 (0..15)

  float acc[4][4];
  {
    const float4 b = ((const float4*)bias)[cg];
    #pragma unroll
    for (int r = 0; r < 4; ++r) {
      acc[r][0] = b.x; acc[r][1] = b.y; acc[r][2] = b.z; acc[r][3] = b.w;
    }
  }

  for (int k0 = 0; k0 < 128; k0 += 4) {
    float av[4][4], wv[4][4];
    #pragma unroll
    for (int j = 0; j < 4; ++j) {
      const float4 w4 = *(const float4*)&Wl[(k0 + j) * 128 + cg * 4];
      wv[j][0] = w4.x; wv[j][1] = w4.y; wv[j][2] = w4.z; wv[j][3] = w4.w;
    }
    #pragma unroll
    for (int r = 0; r < 4; ++r) {
      const float4 a4 = *(const float4*)&Al[(rg * 4 + r) * 132 + k0];
      av[r][0] = a4.x; av[r][1] = a4.y; av[r][2] = a4.z; av[r][3] = a4.w;
    }
    #pragma unroll
    for (int r = 0; r < 4; ++r)
      #pragma unroll
      for (int j = 0; j < 4; ++j)
        #pragma unroll
        for (int c = 0; c < 4; ++c)
          acc[r][c] = fmaf(av[r][j], wv[j][c], acc[r][c]);
  }

  #pragma unroll
  for (int r = 0; r < 4; ++r) {
    const int gr = row0 + rg * 4 + r;
    if (gr < n) {
      float4 o; o.x = acc[r][0]; o.y = acc[r][1]; o.z = acc[r][2]; o.w = acc[r][3];
      ((float4*)C)[(size_t)gr * 32 + cg] = o;
    }
  }
}

// ---------------------------------------------------------------------------
// Edge scatter: agg[dst] += h[src], 32 threads (x float4) per edge
// ---------------------------------------------------------------------------
__global__ __launch_bounds__(256) void scatter_add(
    const float* __restrict__ h, const int* __restrict__ ei,
    float* __restrict__ agg) {
  const int idx = blockIdx.x * 256 + threadIdx.x;
  const int e = idx >> 5;
  const int q = idx & 31;
  if (e >= NE) return;
  const int src = ei[e];
  const int dst = ei[NE + e];
  const float4 v = ((const float4*)h)[(size_t)src * 32 + q];
  float* p = agg + (size_t)dst * 128 + q * 4;
  atomicAdd(p + 0, v.x);
  atomicAdd(p + 1, v.y);
  atomicAdd(p + 2, v.z);
  atomicAdd(p + 3, v.w);
}

// ---------------------------------------------------------------------------
// BN stats: deterministic two-stage column reduction
// ---------------------------------------------------------------------------
__global__ __launch_bounds__(256) void bn_stats_partial(
    const float* __restrict__ Z, int n, float* __restrict__ psum,
    float* __restrict__ psq) {
  const int blk = blockIdx.x;
  const int rows_per = (n + 511) / 512;
  const int r0 = blk * rows_per;
  const int r1 = min(n, r0 + rows_per);
  const int t = threadIdx.x;
  const int c = t & 127;
  const int half = t >> 7;
  float s = 0.f, s2 = 0.f;
  for (int r = r0 + half; r < r1; r += 2) {
    const float v = Z[(size_t)r * 128 + c];
    s += v;
    s2 = fmaf(v, v, s2);
  }
  __shared__ float ls[256], lq[256];
  ls[t] = s; lq[t] = s2;
  __syncthreads();
  if (t < 128) {
    psum[blk * 128 + t] = ls[t] + ls[t + 128];
    psq[blk * 128 + t] = lq[t] + lq[t + 128];
  }
}

__global__ void bn_stats_final(const float* __restrict__ psum,
                               const float* __restrict__ psq,
                               const float* __restrict__ gamma,
                               const float* __restrict__ beta,
                               float* __restrict__ scale,
                               float* __restrict__ shift, int n) {
  const int c = threadIdx.x;  // 128 threads
  float s = 0.f, s2 = 0.f;
  for (int b = 0; b < 512; ++b) {
    s += psum[b * 128 + c];
    s2 += psq[b * 128 + c];
  }
  const float inv_n = 1.f / (float)n;
  const float mu = s * inv_n;
  float var = s2 * inv_n - mu * mu;
  var = fmaxf(var, 0.f);
  const float sc = rsqrtf(var + BN_EPS) * gamma[c];
  scale[c] = sc;
  shift[c] = beta[c] - mu * sc;
}

// ---------------------------------------------------------------------------
// BN apply + ReLU + per-graph pooled accumulation
// ---------------------------------------------------------------------------
__global__ __launch_bounds__(256) void bn_relu_pool(
    const float* __restrict__ Z, const float* __restrict__ scale,
    const float* __restrict__ shift, const int* __restrict__ batch,
    float* __restrict__ h, float* __restrict__ pooled, int layerOff, int n) {
  const int idx = blockIdx.x * 256 + threadIdx.x;
  if (idx >= n * 32) return;
  const int r = idx >> 5;
  const int q = idx & 31;
  const int c = q * 4;
  const float4 v = ((const float4*)Z)[idx];
  float4 o;
  o.x = fmaxf(fmaf(v.x, scale[c + 0], shift[c + 0]), 0.f);
  o.y = fmaxf(fmaf(v.y, scale[c + 1], shift[c + 1]), 0.f);
  o.z = fmaxf(fmaf(v.z, scale[c + 2], shift[c + 2]), 0.f);
  o.w = fmaxf(fmaf(v.w, scale[c + 3], shift[c + 3]), 0.f);
  ((float4*)h)[idx] = o;
  const int g = batch[r];
  float* p = pooled + (size_t)g * 256 + layerOff + c;
  atomicAdd(p + 0, o.x);
  atomicAdd(p + 1, o.y);
  atomicAdd(p + 2, o.z);
  atomicAdd(p + 3, o.w);
}

// ---------------------------------------------------------------------------
// Per-graph counts from sorted batch (deterministic binary search)
// ---------------------------------------------------------------------------
__global__ void compute_counts(const int* __restrict__ batch,
                               float* __restrict__ counts) {
  const int g = blockIdx.x * blockDim.x + threadIdx.x;
  if (g >= NG) return;
  int lo0 = 0, hi0 = NN;
  while (lo0 < hi0) { int m = (lo0 + hi0) >> 1; if (batch[m] < g) lo0 = m + 1; else hi0 = m; }
  int lo1 = 0, hi1 = NN;
  while (lo1 < hi1) { int m = (lo1 + hi1) >> 1; if (batch[m] < g + 1) lo1 = m + 1; else hi1 = m; }
  counts[g] = (float)(lo1 - lo0);
}

// ---------------------------------------------------------------------------
// Final: out[g] = dot(pooled[g,:], jk_w)/max(cnt,1) + jk_b  (one wave/graph)
// ---------------------------------------------------------------------------
__global__ __launch_bounds__(256) void final_out(
    const float* __restrict__ pooled, const float* __restrict__ counts,
    const float* __restrict__ jkw, const float* __restrict__ jkb,
    float* __restrict__ out) {
  const int wave = threadIdx.x >> 6;
  const int lane = threadIdx.x & 63;
  const int g = blockIdx.x * 4 + wave;
  if (g >= NG) return;
  const float4 p = ((const float4*)(pooled + (size_t)g * 256))[lane];
  const float4 w = ((const float4*)jkw)[lane];
  float s = p.x * w.x + p.y * w.y + p.z * w.z + p.w * w.w;
  for (int off = 32; off; off >>= 1) s += __shfl_down(s, off, 64);
  if (lane == 0) out[g] = s / fmaxf(counts[g], 1.f) + jkb[0];
}

// ---------------------------------------------------------------------------
extern "C" void kernel_launch(void* const* d_in, const int* in_sizes, int n_in,
                              void* d_out, int out_size, void* d_ws,
                              size_t ws_size, hipStream_t stream) {
  const float* x     = (const float*)d_in[0];
  const int*   ei    = (const int*)d_in[1];
  const int*   batch = (const int*)d_in[2];
  const float* lin_w = (const float*)d_in[3];
  const float* lin_b = (const float*)d_in[4];
  const float* w1    = (const float*)d_in[5];
  const float* b1    = (const float*)d_in[6];
  const float* g1    = (const float*)d_in[7];
  const float* be1   = (const float*)d_in[8];
  const float* w2    = (const float*)d_in[9];
  const float* b2    = (const float*)d_in[10];
  const float* g2    = (const float*)d_in[11];
  const float* be2   = (const float*)d_in[12];
  const float* jkw   = (const float*)d_in[13];
  const float* jkb   = (const float*)d_in[14];
  float* out = (float*)d_out;

  float* ws = (float*)d_ws;
  float* h      = ws;
  float* agg    = h + (size_t)NN * 128;
  float* z      = agg + (size_t)NN * 128;
  float* psum   = z + (size_t)NN * 128;
  float* psq    = psum + 512 * 128;
  float* scale  = psq + 512 * 128;
  float* shift  = scale + 128;
  float* pooled = shift + 128;
  float* counts = pooled + (size_t)NG * 256;

  hipMemsetAsync(pooled, 0, (size_t)NG * 256 * sizeof(float), stream);
  compute_counts<<<2, 256, 0, stream>>>(batch, counts);

  const int gemm_grid = (NN + 63) / 64;  // 782
  gemm128<0><<<gemm_grid, 512, 0, stream>>>(x, nullptr, nullptr, nullptr,
                                            lin_w, lin_b, h, NN);

  for (int l = 0; l < NL; ++l) {
    hipMemsetAsync(agg, 0, (size_t)NN * 128 * sizeof(float), stream);
    scatter_add<<<NE * 32 / 256, 256, 0, stream>>>(h, ei, agg);
    gemm128<1><<<gemm_grid, 512, 0, stream>>>(h, agg, nullptr, nullptr,
                                              w1 + l * 16384, b1 + l * 128, z, NN);
    bn_stats_partial<<<512, 256, 0, stream>>>(z, NN, psum, psq);
    bn_stats_final<<<1, 128, 0, stream>>>(psum, psq, g1 + l * 128, be1 + l * 128,
                                          scale, shift, NN);
    gemm128<2><<<gemm_grid, 512, 0, stream>>>(z, nullptr, scale, shift,
                                              w2 + l * 16384, b2 + l * 128, agg, NN);
    bn_stats_partial<<<512, 256, 0, stream>>>(agg, NN, psum, psq);
    bn_stats_final<<<1, 128, 0, stream>>>(psum, psq, g2 + l * 128, be2 + l * 128,
                                          scale, shift, NN);
    bn_relu_pool<<<(NN * 32 + 255) / 256, 256, 0, stream>>>(
        agg, scale, shift, batch, h, pooled, l * 128, NN);
  }

  final_out<<<NG / 4, 256, 0, stream>>>(pooled, counts, jkw, jkb, out);
}

// Round 2
// 811.210 us; speedup vs baseline: 3.3952x; 3.3952x over previous
//
#include <hip/hip_runtime.h>
#include <cstddef>

#define NN 50000
#define NE 640000
#define HD 128
#define NG 512
#define NL 2
constexpr float BN_EPS = 1e-5f;

// ---------------------------------------------------------------------------
// GEMM: C[n x 128] = f(A) @ W[128x128] + bias
// MODE 0: f(A) = A
// MODE 2: f(A) = relu(A*scale[k] + shift[k])   (fused BN+ReLU on input)
// 512 threads, 64-row tile, each thread computes 4 rows x 4 cols.
// ---------------------------------------------------------------------------
template <int MODE>
__global__ __launch_bounds__(512) void gemm128(
    const float* __restrict__ A,
    const float* __restrict__ scale, const float* __restrict__ shift,
    const float* __restrict__ W, const float* __restrict__ bias,
    float* __restrict__ C, int n) {
  __shared__ float Wl[128 * 128];
  __shared__ float Al[64 * 132];
  const int t = threadIdx.x;
  const int row0 = blockIdx.x * 64;

  for (int i = t; i < 4096; i += 512) {
    ((float4*)Wl)[i] = ((const float4*)W)[i];
  }
  for (int i = t; i < 2048; i += 512) {
    const int r = i >> 5;
    const int q = i & 31;
    const int gr = row0 + r;
    float4 v;
    if (gr < n) {
      v = ((const float4*)A)[(size_t)gr * 32 + q];
      if (MODE == 2) {
        const int c = q * 4;
        v.x = fmaxf(fmaf(v.x, scale[c + 0], shift[c + 0]), 0.f);
        v.y = fmaxf(fmaf(v.y, scale[c + 1], shift[c + 1]), 0.f);
        v.z = fmaxf(fmaf(v.z, scale[c + 2], shift[c + 2]), 0.f);
        v.w = fmaxf(fmaf(v.w, scale[c + 3], shift[c + 3]), 0.f);
      }
    } else {
      v = make_float4(0.f, 0.f, 0.f, 0.f);
    }
    *(float4*)&Al[r * 132 + q * 4] = v;
  }
  __syncthreads();

  const int cg = t & 31;
  const int rg = t >> 5;

  float acc[4][4];
  {
    const float4 b = ((const float4*)bias)[cg];
    #pragma unroll
    for (int r = 0; r < 4; ++r) {
      acc[r][0] = b.x; acc[r][1] = b.y; acc[r][2] = b.z; acc[r][3] = b.w;
    }
  }

  for (int k0 = 0; k0 < 128; k0 += 4) {
    float av[4][4], wv[4][4];
    #pragma unroll
    for (int j = 0; j < 4; ++j) {
      const float4 w4 = *(const float4*)&Wl[(k0 + j) * 128 + cg * 4];
      wv[j][0] = w4.x; wv[j][1] = w4.y; wv[j][2] = w4.z; wv[j][3] = w4.w;
    }
    #pragma unroll
    for (int r = 0; r < 4; ++r) {
      const float4 a4 = *(const float4*)&Al[(rg * 4 + r) * 132 + k0];
      av[r][0] = a4.x; av[r][1] = a4.y; av[r][2] = a4.z; av[r][3] = a4.w;
    }
    #pragma unroll
    for (int r = 0; r < 4; ++r)
      #pragma unroll
      for (int j = 0; j < 4; ++j)
        #pragma unroll
        for (int c = 0; c < 4; ++c)
          acc[r][c] = fmaf(av[r][j], wv[j][c], acc[r][c]);
  }

  #pragma unroll
  for (int r = 0; r < 4; ++r) {
    const int gr = row0 + rg * 4 + r;
    if (gr < n) {
      float4 o; o.x = acc[r][0]; o.y = acc[r][1]; o.z = acc[r][2]; o.w = acc[r][3];
      ((float4*)C)[(size_t)gr * 32 + cg] = o;
    }
  }
}

// ---------------------------------------------------------------------------
// CSR build (by dst): histogram -> single-block exclusive scan -> bucket fill
// ---------------------------------------------------------------------------
__global__ __launch_bounds__(256) void edge_hist(const int* __restrict__ ei,
                                                 int* __restrict__ cnt) {
  const int e = blockIdx.x * 256 + threadIdx.x;
  if (e >= NE) return;
  atomicAdd(&cnt[ei[NE + e]], 1);
}

__global__ __launch_bounds__(1024) void exscan(const int* __restrict__ cnt,
                                               int* __restrict__ rowptr) {
  __shared__ int part[1024];
  const int t = threadIdx.x;
  const int chunk = (NN + 1023) / 1024;  // 49
  const int b = t * chunk;
  const int e = min(NN, b + chunk);
  int s = 0;
  for (int i = b; i < e; ++i) s += cnt[i];
  part[t] = s;
  __syncthreads();
  for (int off = 1; off < 1024; off <<= 1) {
    int v = (t >= off) ? part[t - off] : 0;
    __syncthreads();
    part[t] += v;
    __syncthreads();
  }
  int excl = (t == 0) ? 0 : part[t - 1];
  for (int i = b; i < e; ++i) { rowptr[i] = excl; excl += cnt[i]; }
  if (t == 1023) rowptr[NN] = part[1023];
}

__global__ __launch_bounds__(256) void build_csr(const int* __restrict__ ei,
                                                 const int* __restrict__ rowptr,
                                                 int* __restrict__ cursor,
                                                 int* __restrict__ srcs) {
  const int e = blockIdx.x * 256 + threadIdx.x;
  if (e >= NE) return;
  const int src = ei[e];
  const int dst = ei[NE + e];
  const int pos = atomicAdd(&cursor[dst], 1);
  srcs[rowptr[dst] + pos] = src;
}

// ---------------------------------------------------------------------------
// Gather-sum per dst: agg[dst] = h[dst] + sum_{src in N(dst)} h[src]
// 32 lanes x float4 per node row.
// ---------------------------------------------------------------------------
__global__ __launch_bounds__(256) void gin_gather(
    const float* __restrict__ h, const int* __restrict__ rowptr,
    const int* __restrict__ srcs, float* __restrict__ agg) {
  const int idx = blockIdx.x * 256 + threadIdx.x;
  const int node = idx >> 5;
  const int q = idx & 31;
  if (node >= NN) return;
  const float4* __restrict__ h4 = (const float4*)h;
  float4 acc = h4[(size_t)node * 32 + q];  // self (GIN eps=0)
  const int beg = rowptr[node];
  const int end = rowptr[node + 1];
  int j = beg;
  for (; j + 1 < end; j += 2) {
    const int s0 = srcs[j];
    const int s1 = srcs[j + 1];
    const float4 v0 = h4[(size_t)s0 * 32 + q];
    const float4 v1 = h4[(size_t)s1 * 32 + q];
    acc.x += v0.x + v1.x; acc.y += v0.y + v1.y;
    acc.z += v0.z + v1.z; acc.w += v0.w + v1.w;
  }
  if (j < end) {
    const float4 v = h4[(size_t)srcs[j] * 32 + q];
    acc.x += v.x; acc.y += v.y; acc.z += v.z; acc.w += v.w;
  }
  ((float4*)agg)[(size_t)node * 32 + q] = acc;
}

// ---------------------------------------------------------------------------
// BN stats: deterministic two-stage column reduction
// ---------------------------------------------------------------------------
__global__ __launch_bounds__(256) void bn_stats_partial(
    const float* __restrict__ Z, int n, float* __restrict__ psum,
    float* __restrict__ psq) {
  const int blk = blockIdx.x;
  const int rows_per = (n + 511) / 512;
  const int r0 = blk * rows_per;
  const int r1 = min(n, r0 + rows_per);
  const int t = threadIdx.x;
  const int c = t & 127;
  const int half = t >> 7;
  float s = 0.f, s2 = 0.f;
  for (int r = r0 + half; r < r1; r += 2) {
    const float v = Z[(size_t)r * 128 + c];
    s += v;
    s2 = fmaf(v, v, s2);
  }
  __shared__ float ls[256], lq[256];
  ls[t] = s; lq[t] = s2;
  __syncthreads();
  if (t < 128) {
    psum[blk * 128 + t] = ls[t] + ls[t + 128];
    psq[blk * 128 + t] = lq[t] + lq[t + 128];
  }
}

__global__ void bn_stats_final(const float* __restrict__ psum,
                               const float* __restrict__ psq,
                               const float* __restrict__ gamma,
                               const float* __restrict__ beta,
                               float* __restrict__ scale,
                               float* __restrict__ shift, int n) {
  const int c = threadIdx.x;  // 128 threads
  float s = 0.f, s2 = 0.f;
  for (int b = 0; b < 512; ++b) {
    s += psum[b * 128 + c];
    s2 += psq[b * 128 + c];
  }
  const float inv_n = 1.f / (float)n;
  const float mu = s * inv_n;
  float var = s2 * inv_n - mu * mu;
  var = fmaxf(var, 0.f);
  const float sc = rsqrtf(var + BN_EPS) * gamma[c];
  scale[c] = sc;
  shift[c] = beta[c] - mu * sc;
}

// ---------------------------------------------------------------------------
// BN apply + ReLU + per-graph pooled accumulation
// ---------------------------------------------------------------------------
__global__ __launch_bounds__(256) void bn_relu_pool(
    const float* __restrict__ Z, const float* __restrict__ scale,
    const float* __restrict__ shift, const int* __restrict__ batch,
    float* __restrict__ h, float* __restrict__ pooled, int layerOff, int n) {
  const int idx = blockIdx.x * 256 + threadIdx.x;
  if (idx >= n * 32) return;
  const int r = idx >> 5;
  const int q = idx & 31;
  const int c = q * 4;
  const float4 v = ((const float4*)Z)[idx];
  float4 o;
  o.x = fmaxf(fmaf(v.x, scale[c + 0], shift[c + 0]), 0.f);
  o.y = fmaxf(fmaf(v.y, scale[c + 1], shift[c + 1]), 0.f);
  o.z = fmaxf(fmaf(v.z, scale[c + 2], shift[c + 2]), 0.f);
  o.w = fmaxf(fmaf(v.w, scale[c + 3], shift[c + 3]), 0.f);
  ((float4*)h)[idx] = o;
  const int g = batch[r];
  float* p = pooled + (size_t)g * 256 + layerOff + c;
  atomicAdd(p + 0, o.x);
  atomicAdd(p + 1, o.y);
  atomicAdd(p + 2, o.z);
  atomicAdd(p + 3, o.w);
}

// ---------------------------------------------------------------------------
__global__ void compute_counts(const int* __restrict__ batch,
                               float* __restrict__ counts) {
  const int g = blockIdx.x * blockDim.x + threadIdx.x;
  if (g >= NG) return;
  int lo0 = 0, hi0 = NN;
  while (lo0 < hi0) { int m = (lo0 + hi0) >> 1; if (batch[m] < g) lo0 = m + 1; else hi0 = m; }
  int lo1 = 0, hi1 = NN;
  while (lo1 < hi1) { int m = (lo1 + hi1) >> 1; if (batch[m] < g + 1) lo1 = m + 1; else hi1 = m; }
  counts[g] = (float)(lo1 - lo0);
}

__global__ __launch_bounds__(256) void final_out(
    const float* __restrict__ pooled, const float* __restrict__ counts,
    const float* __restrict__ jkw, const float* __restrict__ jkb,
    float* __restrict__ out) {
  const int wave = threadIdx.x >> 6;
  const int lane = threadIdx.x & 63;
  const int g = blockIdx.x * 4 + wave;
  if (g >= NG) return;
  const float4 p = ((const float4*)(pooled + (size_t)g * 256))[lane];
  const float4 w = ((const float4*)jkw)[lane];
  float s = p.x * w.x + p.y * w.y + p.z * w.z + p.w * w.w;
  for (int off = 32; off; off >>= 1) s += __shfl_down(s, off, 64);
  if (lane == 0) out[g] = s / fmaxf(counts[g], 1.f) + jkb[0];
}

// ---------------------------------------------------------------------------
extern "C" void kernel_launch(void* const* d_in, const int* in_sizes, int n_in,
                              void* d_out, int out_size, void* d_ws,
                              size_t ws_size, hipStream_t stream) {
  const float* x     = (const float*)d_in[0];
  const int*   ei    = (const int*)d_in[1];
  const int*   batch = (const int*)d_in[2];
  const float* lin_w = (const float*)d_in[3];
  const float* lin_b = (const float*)d_in[4];
  const float* w1    = (const float*)d_in[5];
  const float* b1    = (const float*)d_in[6];
  const float* g1    = (const float*)d_in[7];
  const float* be1   = (const float*)d_in[8];
  const float* w2    = (const float*)d_in[9];
  const float* b2    = (const float*)d_in[10];
  const float* g2    = (const float*)d_in[11];
  const float* be2   = (const float*)d_in[12];
  const float* jkw   = (const float*)d_in[13];
  const float* jkb   = (const float*)d_in[14];
  float* out = (float*)d_out;

  float* ws = (float*)d_ws;
  float* h      = ws;                       // NN*128 (also serves as z)
  float* agg    = h + (size_t)NN * 128;     // NN*128
  float* psum   = agg + (size_t)NN * 128;   // 512*128
  float* psq    = psum + 512 * 128;         // 512*128
  float* scale  = psq + 512 * 128;          // 128
  float* shift  = scale + 128;              // 128
  float* pooled = shift + 128;              // NG*256
  float* counts = pooled + (size_t)NG * 256;  // NG
  int* rowptr = (int*)(counts + NG);        // NN+1
  int* cnt    = rowptr + NN + 1;            // NN
  int* srcs   = cnt + NN;                   // NE

  hipMemsetAsync(pooled, 0, (size_t)NG * 256 * sizeof(float), stream);
  hipMemsetAsync(cnt, 0, (size_t)NN * sizeof(int), stream);
  compute_counts<<<2, 256, 0, stream>>>(batch, counts);

  // ---- CSR build (once; reused by both layers) ----
  edge_hist<<<(NE + 255) / 256, 256, 0, stream>>>(ei, cnt);
  exscan<<<1, 1024, 0, stream>>>(cnt, rowptr);
  hipMemsetAsync(cnt, 0, (size_t)NN * sizeof(int), stream);
  build_csr<<<(NE + 255) / 256, 256, 0, stream>>>(ei, rowptr, cnt, srcs);

  const int gemm_grid = (NN + 63) / 64;  // 782
  gemm128<0><<<gemm_grid, 512, 0, stream>>>(x, nullptr, nullptr,
                                            lin_w, lin_b, h, NN);

  for (int l = 0; l < NL; ++l) {
    gin_gather<<<(NN * 32 + 255) / 256, 256, 0, stream>>>(h, rowptr, srcs, agg);
    // z := (h+agg) @ W1 + b1, stored into h (h dead until bn_relu_pool)
    gemm128<0><<<gemm_grid, 512, 0, stream>>>(agg, nullptr, nullptr,
                                              w1 + l * 16384, b1 + l * 128, h, NN);
    bn_stats_partial<<<512, 256, 0, stream>>>(h, NN, psum, psq);
    bn_stats_final<<<1, 128, 0, stream>>>(psum, psq, g1 + l * 128, be1 + l * 128,
                                          scale, shift, NN);
    gemm128<2><<<gemm_grid, 512, 0, stream>>>(h, scale, shift,
                                              w2 + l * 16384, b2 + l * 128, agg, NN);
    bn_stats_partial<<<512, 256, 0, stream>>>(agg, NN, psum, psq);
    bn_stats_final<<<1, 128, 0, stream>>>(psum, psq, g2 + l * 128, be2 + l * 128,
                                          scale, shift, NN);
    bn_relu_pool<<<(NN * 32 + 255) / 256, 256, 0, stream>>>(
        agg, scale, shift, batch, h, pooled, l * 128, NN);
  }

  final_out<<<NG / 4, 256, 0, stream>>>(pooled, counts, jkw, jkb, out);
}

// Round 3
// 587.428 us; speedup vs baseline: 4.6887x; 1.3810x over previous
//
#include <hip/hip_runtime.h>
#include <cstddef>

#define NN 50000
#define NE 640000
#define HD 128
#define NG 512
#define NL 2
constexpr float BN_EPS = 1e-5f;

// ---------------------------------------------------------------------------
// GEMM: C[n x 128] = f(A) @ W[128x128] + bias
// MODE 0: f(A) = A
// MODE 2: f(A) = relu(A*scale[k] + shift[k])   (fused BN+ReLU on input)
// 512 threads, 64-row tile, each thread computes 4 rows x 4 cols.
// ---------------------------------------------------------------------------
template <int MODE>
__global__ __launch_bounds__(512) void gemm128(
    const float* __restrict__ A,
    const float* __restrict__ scale, const float* __restrict__ shift,
    const float* __restrict__ W, const float* __restrict__ bias,
    float* __restrict__ C, int n) {
  __shared__ float Wl[128 * 128];
  __shared__ float Al[64 * 132];
  const int t = threadIdx.x;
  const int row0 = blockIdx.x * 64;

  for (int i = t; i < 4096; i += 512) {
    ((float4*)Wl)[i] = ((const float4*)W)[i];
  }
  for (int i = t; i < 2048; i += 512) {
    const int r = i >> 5;
    const int q = i & 31;
    const int gr = row0 + r;
    float4 v;
    if (gr < n) {
      v = ((const float4*)A)[(size_t)gr * 32 + q];
      if (MODE == 2) {
        const int c = q * 4;
        v.x = fmaxf(fmaf(v.x, scale[c + 0], shift[c + 0]), 0.f);
        v.y = fmaxf(fmaf(v.y, scale[c + 1], shift[c + 1]), 0.f);
        v.z = fmaxf(fmaf(v.z, scale[c + 2], shift[c + 2]), 0.f);
        v.w = fmaxf(fmaf(v.w, scale[c + 3], shift[c + 3]), 0.f);
      }
    } else {
      v = make_float4(0.f, 0.f, 0.f, 0.f);
    }
    *(float4*)&Al[r * 132 + q * 4] = v;
  }
  __syncthreads();

  const int cg = t & 31;
  const int rg = t >> 5;

  float acc[4][4];
  {
    const float4 b = ((const float4*)bias)[cg];
    #pragma unroll
    for (int r = 0; r < 4; ++r) {
      acc[r][0] = b.x; acc[r][1] = b.y; acc[r][2] = b.z; acc[r][3] = b.w;
    }
  }

  for (int k0 = 0; k0 < 128; k0 += 4) {
    float av[4][4], wv[4][4];
    #pragma unroll
    for (int j = 0; j < 4; ++j) {
      const float4 w4 = *(const float4*)&Wl[(k0 + j) * 128 + cg * 4];
      wv[j][0] = w4.x; wv[j][1] = w4.y; wv[j][2] = w4.z; wv[j][3] = w4.w;
    }
    #pragma unroll
    for (int r = 0; r < 4; ++r) {
      const float4 a4 = *(const float4*)&Al[(rg * 4 + r) * 132 + k0];
      av[r][0] = a4.x; av[r][1] = a4.y; av[r][2] = a4.z; av[r][3] = a4.w;
    }
    #pragma unroll
    for (int r = 0; r < 4; ++r)
      #pragma unroll
      for (int j = 0; j < 4; ++j)
        #pragma unroll
        for (int c = 0; c < 4; ++c)
          acc[r][c] = fmaf(av[r][j], wv[j][c], acc[r][c]);
  }

  #pragma unroll
  for (int r = 0; r < 4; ++r) {
    const int gr = row0 + rg * 4 + r;
    if (gr < n) {
      float4 o; o.x = acc[r][0]; o.y = acc[r][1]; o.z = acc[r][2]; o.w = acc[r][3];
      ((float4*)C)[(size_t)gr * 32 + cg] = o;
    }
  }
}

// ---------------------------------------------------------------------------
// CSR build (by dst): histogram -> single-block exclusive scan -> bucket fill
// ---------------------------------------------------------------------------
__global__ __launch_bounds__(256) void edge_hist(const int* __restrict__ ei,
                                                 int* __restrict__ cnt) {
  const int e = blockIdx.x * 256 + threadIdx.x;
  if (e >= NE) return;
  atomicAdd(&cnt[ei[NE + e]], 1);
}

__global__ __launch_bounds__(1024) void exscan(const int* __restrict__ cnt,
                                               int* __restrict__ rowptr) {
  __shared__ int part[1024];
  const int t = threadIdx.x;
  const int chunk = (NN + 1023) / 1024;  // 49
  const int b = t * chunk;
  const int e = min(NN, b + chunk);
  int s = 0;
  for (int i = b; i < e; ++i) s += cnt[i];
  part[t] = s;
  __syncthreads();
  for (int off = 1; off < 1024; off <<= 1) {
    int v = (t >= off) ? part[t - off] : 0;
    __syncthreads();
    part[t] += v;
    __syncthreads();
  }
  int excl = (t == 0) ? 0 : part[t - 1];
  for (int i = b; i < e; ++i) { rowptr[i] = excl; excl += cnt[i]; }
  if (t == 1023) rowptr[NN] = part[1023];
}

__global__ __launch_bounds__(256) void build_csr(const int* __restrict__ ei,
                                                 const int* __restrict__ rowptr,
                                                 int* __restrict__ cursor,
                                                 int* __restrict__ srcs) {
  const int e = blockIdx.x * 256 + threadIdx.x;
  if (e >= NE) return;
  const int src = ei[e];
  const int dst = ei[NE + e];
  const int pos = atomicAdd(&cursor[dst], 1);
  srcs[rowptr[dst] + pos] = src;
}

// ---------------------------------------------------------------------------
// Gather-sum per dst: agg[dst] = h[dst] + sum_{src in N(dst)} h[src]
// ---------------------------------------------------------------------------
__global__ __launch_bounds__(256) void gin_gather(
    const float* __restrict__ h, const int* __restrict__ rowptr,
    const int* __restrict__ srcs, float* __restrict__ agg) {
  const int idx = blockIdx.x * 256 + threadIdx.x;
  const int node = idx >> 5;
  const int q = idx & 31;
  if (node >= NN) return;
  const float4* __restrict__ h4 = (const float4*)h;
  float4 acc = h4[(size_t)node * 32 + q];  // self (GIN eps=0)
  const int beg = rowptr[node];
  const int end = rowptr[node + 1];
  int j = beg;
  for (; j + 1 < end; j += 2) {
    const int s0 = srcs[j];
    const int s1 = srcs[j + 1];
    const float4 v0 = h4[(size_t)s0 * 32 + q];
    const float4 v1 = h4[(size_t)s1 * 32 + q];
    acc.x += v0.x + v1.x; acc.y += v0.y + v1.y;
    acc.z += v0.z + v1.z; acc.w += v0.w + v1.w;
  }
  if (j < end) {
    const float4 v = h4[(size_t)srcs[j] * 32 + q];
    acc.x += v.x; acc.y += v.y; acc.z += v.z; acc.w += v.w;
  }
  ((float4*)agg)[(size_t)node * 32 + q] = acc;
}

// ---------------------------------------------------------------------------
// BN stats: deterministic two-stage column reduction
// ---------------------------------------------------------------------------
__global__ __launch_bounds__(256) void bn_stats_partial(
    const float* __restrict__ Z, int n, float* __restrict__ psum,
    float* __restrict__ psq) {
  const int blk = blockIdx.x;
  const int rows_per = (n + 511) / 512;
  const int r0 = blk * rows_per;
  const int r1 = min(n, r0 + rows_per);
  const int t = threadIdx.x;
  const int c = t & 127;
  const int half = t >> 7;
  float s = 0.f, s2 = 0.f;
  for (int r = r0 + half; r < r1; r += 2) {
    const float v = Z[(size_t)r * 128 + c];
    s += v;
    s2 = fmaf(v, v, s2);
  }
  __shared__ float ls[256], lq[256];
  ls[t] = s; lq[t] = s2;
  __syncthreads();
  if (t < 128) {
    psum[blk * 128 + t] = ls[t] + ls[t + 128];
    psq[blk * 128 + t] = lq[t] + lq[t + 128];
  }
}

__global__ void bn_stats_final(const float* __restrict__ psum,
                               const float* __restrict__ psq,
                               const float* __restrict__ gamma,
                               const float* __restrict__ beta,
                               float* __restrict__ scale,
                               float* __restrict__ shift, int n) {
  const int c = threadIdx.x;  // 128 threads
  float s = 0.f, s2 = 0.f;
  for (int b = 0; b < 512; ++b) {
    s += psum[b * 128 + c];
    s2 += psq[b * 128 + c];
  }
  const float inv_n = 1.f / (float)n;
  const float mu = s * inv_n;
  float var = s2 * inv_n - mu * mu;
  var = fmaxf(var, 0.f);
  const float sc = rsqrtf(var + BN_EPS) * gamma[c];
  scale[c] = sc;
  shift[c] = beta[c] - mu * sc;
}

// ---------------------------------------------------------------------------
// Per-graph fused BN+ReLU+mean-pool accumulate: one block per graph.
// batch is sorted -> graph g owns rows [gstart[g], gstart[g+1]).
// 256 threads = 8 row-stripes x 32 float4 col-groups. No atomics.
// ---------------------------------------------------------------------------
template <bool WRITE_H>
__global__ __launch_bounds__(256) void bn_relu_pool_seg(
    const float* __restrict__ Z, const float* __restrict__ scale,
    const float* __restrict__ shift, const int* __restrict__ gstart,
    float* __restrict__ h, float* __restrict__ pooled, int layerOff) {
  const int g = blockIdx.x;
  const int r0 = gstart[g];
  const int r1 = gstart[g + 1];
  const int q = threadIdx.x & 31;
  const int rr = threadIdx.x >> 5;  // 0..7
  const int c = q * 4;
  const float4 sc = *(const float4*)&scale[c];
  const float4 sh = *(const float4*)&shift[c];
  float4 acc = make_float4(0.f, 0.f, 0.f, 0.f);
  for (int r = r0 + rr; r < r1; r += 8) {
    const float4 v = ((const float4*)Z)[(size_t)r * 32 + q];
    float4 o;
    o.x = fmaxf(fmaf(v.x, sc.x, sh.x), 0.f);
    o.y = fmaxf(fmaf(v.y, sc.y, sh.y), 0.f);
    o.z = fmaxf(fmaf(v.z, sc.z, sh.z), 0.f);
    o.w = fmaxf(fmaf(v.w, sc.w, sh.w), 0.f);
    if (WRITE_H) ((float4*)h)[(size_t)r * 32 + q] = o;
    acc.x += o.x; acc.y += o.y; acc.z += o.z; acc.w += o.w;
  }
  __shared__ float4 red[256];
  red[threadIdx.x] = acc;
  __syncthreads();
  #pragma unroll
  for (int off = 128; off >= 32; off >>= 1) {
    if (threadIdx.x < off) {
      float4 a = red[threadIdx.x];
      const float4 b = red[threadIdx.x + off];
      a.x += b.x; a.y += b.y; a.z += b.z; a.w += b.w;
      red[threadIdx.x] = a;
    }
    __syncthreads();
  }
  if (threadIdx.x < 32) {
    *(float4*)&pooled[(size_t)g * 256 + layerOff + c] = red[threadIdx.x];
  }
}

// ---------------------------------------------------------------------------
// Graph segment starts + counts from sorted batch (binary search)
// ---------------------------------------------------------------------------
__global__ void compute_segments(const int* __restrict__ batch,
                                 int* __restrict__ gstart,
                                 float* __restrict__ counts) {
  const int g = blockIdx.x * blockDim.x + threadIdx.x;
  if (g > NG) return;
  int lo = 0, hi = NN;
  while (lo < hi) { int m = (lo + hi) >> 1; if (batch[m] < g) lo = m + 1; else hi = m; }
  gstart[g] = lo;
  if (g < NG) {
    int lo1 = lo, hi1 = NN;
    while (lo1 < hi1) { int m = (lo1 + hi1) >> 1; if (batch[m] < g + 1) lo1 = m + 1; else hi1 = m; }
    counts[g] = (float)(lo1 - lo);
  }
}

__global__ __launch_bounds__(256) void final_out(
    const float* __restrict__ pooled, const float* __restrict__ counts,
    const float* __restrict__ jkw, const float* __restrict__ jkb,
    float* __restrict__ out) {
  const int wave = threadIdx.x >> 6;
  const int lane = threadIdx.x & 63;
  const int g = blockIdx.x * 4 + wave;
  if (g >= NG) return;
  const float4 p = ((const float4*)(pooled + (size_t)g * 256))[lane];
  const float4 w = ((const float4*)jkw)[lane];
  float s = p.x * w.x + p.y * w.y + p.z * w.z + p.w * w.w;
  for (int off = 32; off; off >>= 1) s += __shfl_down(s, off, 64);
  if (lane == 0) out[g] = s / fmaxf(counts[g], 1.f) + jkb[0];
}

// ---------------------------------------------------------------------------
extern "C" void kernel_launch(void* const* d_in, const int* in_sizes, int n_in,
                              void* d_out, int out_size, void* d_ws,
                              size_t ws_size, hipStream_t stream) {
  const float* x     = (const float*)d_in[0];
  const int*   ei    = (const int*)d_in[1];
  const int*   batch = (const int*)d_in[2];
  const float* lin_w = (const float*)d_in[3];
  const float* lin_b = (const float*)d_in[4];
  const float* w1    = (const float*)d_in[5];
  const float* b1    = (const float*)d_in[6];
  const float* g1    = (const float*)d_in[7];
  const float* be1   = (const float*)d_in[8];
  const float* w2    = (const float*)d_in[9];
  const float* b2    = (const float*)d_in[10];
  const float* g2    = (const float*)d_in[11];
  const float* be2   = (const float*)d_in[12];
  const float* jkw   = (const float*)d_in[13];
  const float* jkb   = (const float*)d_in[14];
  float* out = (float*)d_out;

  float* ws = (float*)d_ws;
  float* h      = ws;                       // NN*128 (also serves as z)
  float* agg    = h + (size_t)NN * 128;     // NN*128
  float* psum   = agg + (size_t)NN * 128;   // 512*128
  float* psq    = psum + 512 * 128;         // 512*128
  float* scale  = psq + 512 * 128;          // 128
  float* shift  = scale + 128;              // 128
  float* pooled = shift + 128;              // NG*256
  float* counts = pooled + (size_t)NG * 256;  // NG
  int* gstart = (int*)(counts + NG);        // NG+1
  int* rowptr = gstart + NG + 1;            // NN+1
  int* cnt    = rowptr + NN + 1;            // NN
  int* srcs   = cnt + NN;                   // NE

  hipMemsetAsync(cnt, 0, (size_t)NN * sizeof(int), stream);
  compute_segments<<<3, 256, 0, stream>>>(batch, gstart, counts);

  // ---- CSR build (once; reused by both layers) ----
  edge_hist<<<(NE + 255) / 256, 256, 0, stream>>>(ei, cnt);
  exscan<<<1, 1024, 0, stream>>>(cnt, rowptr);
  hipMemsetAsync(cnt, 0, (size_t)NN * sizeof(int), stream);
  build_csr<<<(NE + 255) / 256, 256, 0, stream>>>(ei, rowptr, cnt, srcs);

  const int gemm_grid = (NN + 63) / 64;  // 782
  gemm128<0><<<gemm_grid, 512, 0, stream>>>(x, nullptr, nullptr,
                                            lin_w, lin_b, h, NN);

  for (int l = 0; l < NL; ++l) {
    gin_gather<<<(NN * 32 + 255) / 256, 256, 0, stream>>>(h, rowptr, srcs, agg);
    gemm128<0><<<gemm_grid, 512, 0, stream>>>(agg, nullptr, nullptr,
                                              w1 + l * 16384, b1 + l * 128, h, NN);
    bn_stats_partial<<<512, 256, 0, stream>>>(h, NN, psum, psq);
    bn_stats_final<<<1, 128, 0, stream>>>(psum, psq, g1 + l * 128, be1 + l * 128,
                                          scale, shift, NN);
    gemm128<2><<<gemm_grid, 512, 0, stream>>>(h, scale, shift,
                                              w2 + l * 16384, b2 + l * 128, agg, NN);
    bn_stats_partial<<<512, 256, 0, stream>>>(agg, NN, psum, psq);
    bn_stats_final<<<1, 128, 0, stream>>>(psum, psq, g2 + l * 128, be2 + l * 128,
                                          scale, shift, NN);
    if (l + 1 < NL) {
      bn_relu_pool_seg<true><<<NG, 256, 0, stream>>>(
          agg, scale, shift, gstart, h, pooled, l * 128);
    } else {
      bn_relu_pool_seg<false><<<NG, 256, 0, stream>>>(
          agg, scale, shift, gstart, h, pooled, l * 128);
    }
  }

  final_out<<<NG / 4, 256, 0, stream>>>(pooled, counts, jkw, jkb, out);
}

// Round 4
// 373.372 us; speedup vs baseline: 7.3767x; 1.5733x over previous
//
#include <hip/hip_runtime.h>
#include <cstddef>

#define NN 50000
#define NE 640000
#define NG 512
#define NL 2
constexpr float BN_EPS = 1e-5f;

typedef __attribute__((ext_vector_type(8))) short bf16x8;
typedef __attribute__((ext_vector_type(16))) float f32x16;

__device__ inline float b2f(unsigned short u) {
  union { unsigned int i; float f; } v; v.i = ((unsigned int)u) << 16; return v.f;
}
__device__ inline float b2f_lo(unsigned int u) {
  union { unsigned int i; float f; } v; v.i = u << 16; return v.f;
}
__device__ inline float b2f_hi(unsigned int u) {
  union { unsigned int i; float f; } v; v.i = u & 0xffff0000u; return v.f;
}
__device__ inline unsigned short f2b(float f) {
  union { float f; unsigned int i; } v; v.f = f;
  return (unsigned short)((v.i + 0x7fffu + ((v.i >> 16) & 1u)) >> 16);
}
__device__ inline unsigned int pack2(float lo, float hi) {
  return (unsigned int)f2b(lo) | ((unsigned int)f2b(hi) << 16);
}
// swizzled LDS byte offset for [row][256B]; keeps 16B alignment, bijective per row
__device__ inline int swz(int row, int b) { return row * 256 + (b ^ ((row & 15) << 4)); }

// ---------------------------------------------------------------------------
// MFMA GEMM: C[n x 128](bf16) = f(A[n x 128](bf16)) @ W[128x128] + bias
// Wt is W transposed (Wt[n][k]) in bf16. MODE 0: identity; MODE 2: BN+ReLU.
// 256 thr = 4 waves; 64-row tile; wave w: rows (w&1)*32, cols (w>>1)*64.
// In-place safe (block stages its own rows before writing them).
// ---------------------------------------------------------------------------
template <int MODE>
__global__ __launch_bounds__(256) void gemm_mfma(
    const unsigned short* __restrict__ A, const float* __restrict__ scale,
    const float* __restrict__ shift, const unsigned short* __restrict__ Wt,
    const float* __restrict__ bias, unsigned short* __restrict__ C, int n) {
  __shared__ uint4 ldsbuf[3072];  // 48 KB
  char* Al = (char*)ldsbuf;         // 16 KB  [64][256B] swizzled
  char* Wl = (char*)ldsbuf + 16384; // 32 KB  [128][256B] swizzled
  const int t = threadIdx.x;
  const int row0 = blockIdx.x * 64;

  #pragma unroll
  for (int ii = 0; ii < 8; ++ii) {
    const int i = t + ii * 256;
    const int r = i >> 4;
    const int u = (i & 15) << 4;
    const uint4 v = *(const uint4*)((const char*)Wt + r * 256 + u);
    *(uint4*)(Wl + swz(r, u)) = v;
  }
  #pragma unroll
  for (int ii = 0; ii < 4; ++ii) {
    const int i = t + ii * 256;
    const int r = i >> 4;
    const int u = (i & 15) << 4;
    const int gr = row0 + r;
    uint4 v = make_uint4(0u, 0u, 0u, 0u);
    if (gr < n) {
      v = *(const uint4*)((const char*)A + (size_t)gr * 256 + u);
      if (MODE == 2) {
        const int c0 = u >> 1;
        unsigned int pw[4] = {v.x, v.y, v.z, v.w};
        #pragma unroll
        for (int p = 0; p < 4; ++p) {
          float lo = b2f_lo(pw[p]);
          float hi = b2f_hi(pw[p]);
          lo = fmaxf(fmaf(lo, scale[c0 + 2 * p], shift[c0 + 2 * p]), 0.f);
          hi = fmaxf(fmaf(hi, scale[c0 + 2 * p + 1], shift[c0 + 2 * p + 1]), 0.f);
          pw[p] = pack2(lo, hi);
        }
        v = make_uint4(pw[0], pw[1], pw[2], pw[3]);
      }
    }
    *(uint4*)(Al + swz(r, u)) = v;
  }
  __syncthreads();

  const int w = t >> 6;
  const int l = t & 63;
  const int lane31 = l & 31;
  const int khalf = l >> 5;
  const int mrow = (w & 1) * 32;
  const int c0 = (w >> 1) * 64;

  f32x16 acc0, acc1;
  #pragma unroll
  for (int i = 0; i < 16; ++i) { acc0[i] = 0.f; acc1[i] = 0.f; }

  #pragma unroll
  for (int k0 = 0; k0 < 128; k0 += 16) {
    const int kb = (k0 + 8 * khalf) * 2;
    const bf16x8 a  = *(const bf16x8*)(Al + swz(mrow + lane31, kb));
    const bf16x8 b0 = *(const bf16x8*)(Wl + swz(c0 + lane31, kb));
    const bf16x8 b1 = *(const bf16x8*)(Wl + swz(c0 + 32 + lane31, kb));
    acc0 = __builtin_amdgcn_mfma_f32_32x32x16_bf16(a, b0, acc0, 0, 0, 0);
    acc1 = __builtin_amdgcn_mfma_f32_32x32x16_bf16(a, b1, acc1, 0, 0, 0);
  }

  const float bias0 = bias[c0 + lane31];
  const float bias1 = bias[c0 + 32 + lane31];
  #pragma unroll
  for (int r = 0; r < 16; ++r) {
    const int row = mrow + (r & 3) + 8 * (r >> 2) + 4 * khalf;
    const int grow = row0 + row;
    if (grow < n) {
      C[(size_t)grow * 128 + c0 + lane31] = f2b(acc0[r] + bias0);
      C[(size_t)grow * 128 + c0 + 32 + lane31] = f2b(acc1[r] + bias1);
    }
  }
}

// ---------------------------------------------------------------------------
// Input / weight conversion to bf16 (weights transposed)
// ---------------------------------------------------------------------------
__global__ __launch_bounds__(256) void conv_x_k(const float* __restrict__ x,
                                                unsigned short* __restrict__ xb) {
  const int i = blockIdx.x * 256 + threadIdx.x;  // 16B output unit
  if (i >= NN * 16) return;
  const float4 a = ((const float4*)x)[i * 2];
  const float4 b = ((const float4*)x)[i * 2 + 1];
  uint4 o;
  o.x = pack2(a.x, a.y); o.y = pack2(a.z, a.w);
  o.z = pack2(b.x, b.y); o.w = pack2(b.z, b.w);
  ((uint4*)xb)[i] = o;
}

__global__ __launch_bounds__(256) void conv_w_k(
    const float* __restrict__ lw, const float* __restrict__ w1,
    const float* __restrict__ w2, unsigned short* __restrict__ Wt) {
  const int i = blockIdx.x * 256 + threadIdx.x;
  if (i >= 5 * 16384) return;
  const int m = i >> 14, r = i & 16383;
  const int ncol = r >> 7, k = r & 127;
  const float* src = (m == 0) ? lw : (m <= 2) ? (w1 + (m - 1) * 16384)
                                              : (w2 + (m - 3) * 16384);
  Wt[i] = f2b(src[k * 128 + ncol]);
}

// ---------------------------------------------------------------------------
// CSR build: histogram -> hierarchical scan (3 tiny kernels) -> bucket fill
// ---------------------------------------------------------------------------
#define SCAN_B 196
__global__ __launch_bounds__(256) void edge_hist(const int* __restrict__ ei,
                                                 int* __restrict__ cnt) {
  const int e = blockIdx.x * 256 + threadIdx.x;
  if (e >= NE) return;
  atomicAdd(&cnt[ei[NE + e]], 1);
}

__global__ __launch_bounds__(256) void scan1(const int* __restrict__ cnt,
                                             int* __restrict__ rowptr,
                                             int* __restrict__ bsum) {
  __shared__ int s[256];
  const int b = blockIdx.x, t = threadIdx.x;
  const int i = b * 256 + t;
  const int v = (i < NN) ? cnt[i] : 0;
  s[t] = v;
  __syncthreads();
  for (int off = 1; off < 256; off <<= 1) {
    const int x = (t >= off) ? s[t - off] : 0;
    __syncthreads();
    s[t] += x;
    __syncthreads();
  }
  if (i < NN) rowptr[i] = s[t] - v;
  if (t == 255) bsum[b] = s[255];
}

__global__ __launch_bounds__(256) void scan2(const int* __restrict__ bsum,
                                             int* __restrict__ boff,
                                             int* __restrict__ rowptrN) {
  __shared__ int s[256];
  const int t = threadIdx.x;
  const int v = (t < SCAN_B) ? bsum[t] : 0;
  s[t] = v;
  __syncthreads();
  for (int off = 1; off < 256; off <<= 1) {
    const int x = (t >= off) ? s[t - off] : 0;
    __syncthreads();
    s[t] += x;
    __syncthreads();
  }
  if (t < SCAN_B) boff[t] = s[t] - v;
  if (t == 255) *rowptrN = s[255];
}

__global__ __launch_bounds__(256) void scan3(int* __restrict__ rowptr,
                                             const int* __restrict__ boff) {
  const int i = blockIdx.x * 256 + threadIdx.x;
  if (i < NN) rowptr[i] += boff[blockIdx.x];
}

__global__ __launch_bounds__(256) void build_csr(const int* __restrict__ ei,
                                                 const int* __restrict__ rowptr,
                                                 int* __restrict__ cursor,
                                                 int* __restrict__ srcs) {
  const int e = blockIdx.x * 256 + threadIdx.x;
  if (e >= NE) return;
  const int src = ei[e];
  const int dst = ei[NE + e];
  const int pos = atomicAdd(&cursor[dst], 1);
  srcs[rowptr[dst] + pos] = src;
}

// ---------------------------------------------------------------------------
// Gather-sum (bf16): agg[dst] = h[dst] + sum_{src in N(dst)} h[src]
// 16 lanes x 16B (8 bf16) per node row.
// ---------------------------------------------------------------------------
__global__ __launch_bounds__(256) void gin_gather_b(
    const unsigned short* __restrict__ h, const int* __restrict__ rowptr,
    const int* __restrict__ srcs, unsigned short* __restrict__ agg) {
  const int idx = blockIdx.x * 256 + threadIdx.x;
  const int node = idx >> 4;
  const int q = idx & 15;
  if (node >= NN) return;
  const uint4* h4 = (const uint4*)h;
  float a[8];
  {
    const uint4 v = h4[(size_t)node * 16 + q];
    a[0] = b2f_lo(v.x); a[1] = b2f_hi(v.x); a[2] = b2f_lo(v.y); a[3] = b2f_hi(v.y);
    a[4] = b2f_lo(v.z); a[5] = b2f_hi(v.z); a[6] = b2f_lo(v.w); a[7] = b2f_hi(v.w);
  }
  const int beg = rowptr[node], end = rowptr[node + 1];
  for (int j = beg; j < end; ++j) {
    const uint4 v = h4[(size_t)srcs[j] * 16 + q];
    a[0] += b2f_lo(v.x); a[1] += b2f_hi(v.x); a[2] += b2f_lo(v.y); a[3] += b2f_hi(v.y);
    a[4] += b2f_lo(v.z); a[5] += b2f_hi(v.z); a[6] += b2f_lo(v.w); a[7] += b2f_hi(v.w);
  }
  uint4 o;
  o.x = pack2(a[0], a[1]); o.y = pack2(a[2], a[3]);
  o.z = pack2(a[4], a[5]); o.w = pack2(a[6], a[7]);
  ((uint4*)agg)[(size_t)node * 16 + q] = o;
}

// ---------------------------------------------------------------------------
// BN stats (bf16 input): deterministic two-stage column reduction
// ---------------------------------------------------------------------------
__global__ __launch_bounds__(256) void bn_stats_partial_b(
    const unsigned short* __restrict__ Z, float* __restrict__ psum,
    float* __restrict__ psq) {
  const int blk = blockIdx.x;
  const int rows_per = (NN + 511) / 512;
  const int r0 = blk * rows_per;
  const int r1 = min(NN, r0 + rows_per);
  const int t = threadIdx.x;
  const int c = t & 127;
  const int half = t >> 7;
  float s = 0.f, s2 = 0.f;
  for (int r = r0 + half; r < r1; r += 2) {
    const float v = b2f(Z[(size_t)r * 128 + c]);
    s += v;
    s2 = fmaf(v, v, s2);
  }
  __shared__ float ls[256], lq[256];
  ls[t] = s; lq[t] = s2;
  __syncthreads();
  if (t < 128) {
    psum[blk * 128 + t] = ls[t] + ls[t + 128];
    psq[blk * 128 + t] = lq[t] + lq[t + 128];
  }
}

__global__ void bn_stats_final(const float* __restrict__ psum,
                               const float* __restrict__ psq,
                               const float* __restrict__ gamma,
                               const float* __restrict__ beta,
                               float* __restrict__ scale,
                               float* __restrict__ shift, int n) {
  const int c = threadIdx.x;  // 128 threads
  float s = 0.f, s2 = 0.f;
  for (int b = 0; b < 512; ++b) {
    s += psum[b * 128 + c];
    s2 += psq[b * 128 + c];
  }
  const float inv_n = 1.f / (float)n;
  const float mu = s * inv_n;
  float var = s2 * inv_n - mu * mu;
  var = fmaxf(var, 0.f);
  const float sc = rsqrtf(var + BN_EPS) * gamma[c];
  scale[c] = sc;
  shift[c] = beta[c] - mu * sc;
}

// ---------------------------------------------------------------------------
// Per-graph fused BN+ReLU+mean-pool accumulate (bf16 in, fp32 pooled out)
// ---------------------------------------------------------------------------
template <bool WRITE_H>
__global__ __launch_bounds__(256) void bn_relu_pool_seg_b(
    const unsigned short* __restrict__ Z, const float* __restrict__ scale,
    const float* __restrict__ shift, const int* __restrict__ gstart,
    unsigned short* __restrict__ h, float* __restrict__ pooled, int layerOff) {
  const int g = blockIdx.x;
  const int r0 = gstart[g], r1 = gstart[g + 1];
  const int t = threadIdx.x;
  const int q = t & 15;
  const int rr = t >> 4;
  const int c0 = q * 8;
  float sc[8], sh[8], acc[8];
  #pragma unroll
  for (int i = 0; i < 8; ++i) { sc[i] = scale[c0 + i]; sh[i] = shift[c0 + i]; acc[i] = 0.f; }
  for (int r = r0 + rr; r < r1; r += 16) {
    const uint4 v = ((const uint4*)Z)[(size_t)r * 16 + q];
    float o[8];
    o[0] = b2f_lo(v.x); o[1] = b2f_hi(v.x); o[2] = b2f_lo(v.y); o[3] = b2f_hi(v.y);
    o[4] = b2f_lo(v.z); o[5] = b2f_hi(v.z); o[6] = b2f_lo(v.w); o[7] = b2f_hi(v.w);
    #pragma unroll
    for (int i = 0; i < 8; ++i) {
      o[i] = fmaxf(fmaf(o[i], sc[i], sh[i]), 0.f);
      acc[i] += o[i];
    }
    if (WRITE_H) {
      uint4 ov;
      ov.x = pack2(o[0], o[1]); ov.y = pack2(o[2], o[3]);
      ov.z = pack2(o[4], o[5]); ov.w = pack2(o[6], o[7]);
      ((uint4*)h)[(size_t)r * 16 + q] = ov;
    }
  }
  __shared__ float red[256 * 8];
  #pragma unroll
  for (int i = 0; i < 8; ++i) red[t * 8 + i] = acc[i];
  __syncthreads();
  for (int off = 8; off >= 1; off >>= 1) {
    if (rr < off) {
      #pragma unroll
      for (int i = 0; i < 8; ++i)
        red[t * 8 + i] += red[(t + off * 16) * 8 + i];
    }
    __syncthreads();
  }
  if (rr == 0) {
    #pragma unroll
    for (int i = 0; i < 8; ++i)
      pooled[(size_t)g * 256 + layerOff + c0 + i] = red[t * 8 + i];
  }
}

// ---------------------------------------------------------------------------
__global__ void compute_segments(const int* __restrict__ batch,
                                 int* __restrict__ gstart,
                                 float* __restrict__ counts) {
  const int g = blockIdx.x * blockDim.x + threadIdx.x;
  if (g > NG) return;
  int lo = 0, hi = NN;
  while (lo < hi) { int m = (lo + hi) >> 1; if (batch[m] < g) lo = m + 1; else hi = m; }
  gstart[g] = lo;
  if (g < NG) {
    int lo1 = lo, hi1 = NN;
    while (lo1 < hi1) { int m = (lo1 + hi1) >> 1; if (batch[m] < g + 1) lo1 = m + 1; else hi1 = m; }
    counts[g] = (float)(lo1 - lo);
  }
}

__global__ __launch_bounds__(256) void final_out(
    const float* __restrict__ pooled, const float* __restrict__ counts,
    const float* __restrict__ jkw, const float* __restrict__ jkb,
    float* __restrict__ out) {
  const int wave = threadIdx.x >> 6;
  const int lane = threadIdx.x & 63;
  const int g = blockIdx.x * 4 + wave;
  if (g >= NG) return;
  const float4 p = ((const float4*)(pooled + (size_t)g * 256))[lane];
  const float4 w = ((const float4*)jkw)[lane];
  float s = p.x * w.x + p.y * w.y + p.z * w.z + p.w * w.w;
  for (int off = 32; off; off >>= 1) s += __shfl_down(s, off, 64);
  if (lane == 0) out[g] = s / fmaxf(counts[g], 1.f) + jkb[0];
}

// ---------------------------------------------------------------------------
extern "C" void kernel_launch(void* const* d_in, const int* in_sizes, int n_in,
                              void* d_out, int out_size, void* d_ws,
                              size_t ws_size, hipStream_t stream) {
  const float* x     = (const float*)d_in[0];
  const int*   ei    = (const int*)d_in[1];
  const int*   batch = (const int*)d_in[2];
  const float* lin_w = (const float*)d_in[3];
  const float* lin_b = (const float*)d_in[4];
  const float* w1    = (const float*)d_in[5];
  const float* b1    = (const float*)d_in[6];
  const float* g1    = (const float*)d_in[7];
  const float* be1   = (const float*)d_in[8];
  const float* w2    = (const float*)d_in[9];
  const float* b2    = (const float*)d_in[10];
  const float* g2    = (const float*)d_in[11];
  const float* be2   = (const float*)d_in[12];
  const float* jkw   = (const float*)d_in[13];
  const float* jkb   = (const float*)d_in[14];
  float* out = (float*)d_out;

  char* base = (char*)d_ws;
  unsigned short* xb  = (unsigned short*)base;                 // NN*128 bf16
  unsigned short* hb  = xb + (size_t)NN * 128;                 // NN*128
  unsigned short* agb = hb + (size_t)NN * 128;                 // NN*128
  unsigned short* WtA = agb + (size_t)NN * 128;                // 5*16384
  float* psum   = (float*)(WtA + 5 * 16384);                   // 512*128
  float* psq    = psum + 512 * 128;                            // 512*128
  float* scale  = psq + 512 * 128;                             // 128
  float* shift  = scale + 128;                                 // 128
  float* pooled = shift + 128;                                 // NG*256
  float* counts = pooled + (size_t)NG * 256;                   // NG
  int* gstart = (int*)(counts + NG);                           // NG+1 (+pad)
  int* rowptr = gstart + NG + 4;                               // NN+1 (+pad)
  int* cnt    = rowptr + NN + 4;                               // NN
  int* bsum   = cnt + NN;                                      // 196 (+pad)
  int* boff   = bsum + 200;                                    // 196 (+pad)
  int* srcs   = boff + 200;                                    // NE

  hipMemsetAsync(cnt, 0, (size_t)NN * sizeof(int), stream);
  conv_x_k<<<(NN * 16 + 255) / 256, 256, 0, stream>>>(x, xb);
  conv_w_k<<<(5 * 16384 + 255) / 256, 256, 0, stream>>>(lin_w, w1, w2, WtA);
  compute_segments<<<3, 256, 0, stream>>>(batch, gstart, counts);

  // CSR build (by dst)
  edge_hist<<<(NE + 255) / 256, 256, 0, stream>>>(ei, cnt);
  scan1<<<SCAN_B, 256, 0, stream>>>(cnt, rowptr, bsum);
  scan2<<<1, 256, 0, stream>>>(bsum, boff, rowptr + NN);
  scan3<<<SCAN_B, 256, 0, stream>>>(rowptr, boff);
  hipMemsetAsync(cnt, 0, (size_t)NN * sizeof(int), stream);
  build_csr<<<(NE + 255) / 256, 256, 0, stream>>>(ei, rowptr, cnt, srcs);

  const int gemm_grid = (NN + 63) / 64;  // 782
  gemm_mfma<0><<<gemm_grid, 256, 0, stream>>>(xb, nullptr, nullptr, WtA,
                                              lin_b, hb, NN);

  for (int l = 0; l < NL; ++l) {
    gin_gather_b<<<(NN * 16 + 255) / 256, 256, 0, stream>>>(hb, rowptr, srcs, agb);
    gemm_mfma<0><<<gemm_grid, 256, 0, stream>>>(
        agb, nullptr, nullptr, WtA + (1 + l) * 16384, b1 + l * 128, agb, NN);
    bn_stats_partial_b<<<512, 256, 0, stream>>>(agb, psum, psq);
    bn_stats_final<<<1, 128, 0, stream>>>(psum, psq, g1 + l * 128, be1 + l * 128,
                                          scale, shift, NN);
    gemm_mfma<2><<<gemm_grid, 256, 0, stream>>>(
        agb, scale, shift, WtA + (3 + l) * 16384, b2 + l * 128, agb, NN);
    bn_stats_partial_b<<<512, 256, 0, stream>>>(agb, psum, psq);
    bn_stats_final<<<1, 128, 0, stream>>>(psum, psq, g2 + l * 128, be2 + l * 128,
                                          scale, shift, NN);
    if (l + 1 < NL) {
      bn_relu_pool_seg_b<true><<<NG, 256, 0, stream>>>(
          agb, scale, shift, gstart, hb, pooled, l * 128);
    } else {
      bn_relu_pool_seg_b<false><<<NG, 256, 0, stream>>>(
          agb, scale, shift, gstart, hb, pooled, l * 128);
    }
  }

  final_out<<<NG / 4, 256, 0, stream>>>(pooled, counts, jkw, jkb, out);
}

// Round 5
// 301.713 us; speedup vs baseline: 9.1287x; 1.2375x over previous
//
#include <hip/hip_runtime.h>
#include <cstddef>

#define NN 50000
#define NE 640000
#define NG 512
#define NL 2
#define NSLOT 16
constexpr float BN_EPS = 1e-5f;

typedef __attribute__((ext_vector_type(8))) short bf16x8;
typedef __attribute__((ext_vector_type(16))) float f32x16;

__device__ inline float b2f_lo(unsigned int u) {
  union { unsigned int i; float f; } v; v.i = u << 16; return v.f;
}
__device__ inline float b2f_hi(unsigned int u) {
  union { unsigned int i; float f; } v; v.i = u & 0xffff0000u; return v.f;
}
__device__ inline unsigned short f2b(float f) {
  union { float f; unsigned int i; } v; v.f = f;
  return (unsigned short)((v.i + 0x7fffu + ((v.i >> 16) & 1u)) >> 16);
}
__device__ inline unsigned int pack2(float lo, float hi) {
  return (unsigned int)f2b(lo) | ((unsigned int)f2b(hi) << 16);
}
// swizzled LDS byte offset for [row][256B]; 16B-aligned, bijective per row
__device__ inline int swz(int row, int b) { return row * 256 + (b ^ ((row & 15) << 4)); }

// ---------------------------------------------------------------------------
// Fused MFMA GEMM: C[n x 128](bf16) = f(A) @ W + bias, optional column stats.
// MODE 1: f = CSR gather-sum of bf16 h (GIN agg incl. self)
// MODE 2: f = relu(A*scale + shift), bf16 A (in-place safe)
// MODE 3: f = A, fp32 A
// 256 thr = 4 waves; 64-row tile; wave w: rows (w&1)*32, cols (w>>1)*64.
// ---------------------------------------------------------------------------
template <int MODE, bool STATS>
__global__ __launch_bounds__(256) void gemm_fused(
    const void* __restrict__ Ain, const float* __restrict__ scale,
    const float* __restrict__ shift, const int* __restrict__ rowptr,
    const int* __restrict__ srcs, const unsigned short* __restrict__ Wt,
    const float* __restrict__ bias, unsigned short* __restrict__ C,
    float* __restrict__ psum, float* __restrict__ psq, int n) {
  __shared__ char Wl[32768];
  __shared__ char Al[16384];
  __shared__ float colsum[128];
  __shared__ float colsq[128];
  const int t = threadIdx.x;
  const int row0 = blockIdx.x * 64;

  if (STATS && t < 128) { colsum[t] = 0.f; colsq[t] = 0.f; }

  // ---- stage W (swizzled) ----
  #pragma unroll
  for (int ii = 0; ii < 8; ++ii) {
    const int i = t + ii * 256;
    const int r = i >> 4;
    const int u = (i & 15) << 4;
    *(uint4*)(Wl + swz(r, u)) = *(const uint4*)((const char*)Wt + r * 256 + u);
  }

  // ---- stage A (swizzled), per MODE ----
  if (MODE == 1) {
    const uint4* h4 = (const uint4*)Ain;
    const int q = t & 15;
    const int grp = t >> 4;
    #pragma unroll
    for (int i = 0; i < 4; ++i) {
      const int ln = grp * 4 + i;
      const int gr = row0 + ln;
      float a0[8] = {0.f, 0.f, 0.f, 0.f, 0.f, 0.f, 0.f, 0.f};
      float a1[8] = {0.f, 0.f, 0.f, 0.f, 0.f, 0.f, 0.f, 0.f};
      if (gr < n) {
        {
          const uint4 v = h4[(size_t)gr * 16 + q];
          a0[0] = b2f_lo(v.x); a0[1] = b2f_hi(v.x); a0[2] = b2f_lo(v.y); a0[3] = b2f_hi(v.y);
          a0[4] = b2f_lo(v.z); a0[5] = b2f_hi(v.z); a0[6] = b2f_lo(v.w); a0[7] = b2f_hi(v.w);
        }
        const int beg = rowptr[gr], end = rowptr[gr + 1];
        int j = beg;
        for (; j + 1 < end; j += 2) {
          const uint4 v0 = h4[(size_t)srcs[j] * 16 + q];
          const uint4 v1 = h4[(size_t)srcs[j + 1] * 16 + q];
          a0[0] += b2f_lo(v0.x); a0[1] += b2f_hi(v0.x); a0[2] += b2f_lo(v0.y); a0[3] += b2f_hi(v0.y);
          a0[4] += b2f_lo(v0.z); a0[5] += b2f_hi(v0.z); a0[6] += b2f_lo(v0.w); a0[7] += b2f_hi(v0.w);
          a1[0] += b2f_lo(v1.x); a1[1] += b2f_hi(v1.x); a1[2] += b2f_lo(v1.y); a1[3] += b2f_hi(v1.y);
          a1[4] += b2f_lo(v1.z); a1[5] += b2f_hi(v1.z); a1[6] += b2f_lo(v1.w); a1[7] += b2f_hi(v1.w);
        }
        if (j < end) {
          const uint4 v0 = h4[(size_t)srcs[j] * 16 + q];
          a0[0] += b2f_lo(v0.x); a0[1] += b2f_hi(v0.x); a0[2] += b2f_lo(v0.y); a0[3] += b2f_hi(v0.y);
          a0[4] += b2f_lo(v0.z); a0[5] += b2f_hi(v0.z); a0[6] += b2f_lo(v0.w); a0[7] += b2f_hi(v0.w);
        }
        #pragma unroll
        for (int p = 0; p < 8; ++p) a0[p] += a1[p];
      }
      uint4 o;
      o.x = pack2(a0[0], a0[1]); o.y = pack2(a0[2], a0[3]);
      o.z = pack2(a0[4], a0[5]); o.w = pack2(a0[6], a0[7]);
      *(uint4*)(Al + swz(ln, q * 16)) = o;
    }
  } else {
    #pragma unroll
    for (int ii = 0; ii < 4; ++ii) {
      const int i = t + ii * 256;
      const int r = i >> 4;
      const int u = (i & 15) << 4;
      const int gr = row0 + r;
      uint4 v = make_uint4(0u, 0u, 0u, 0u);
      if (gr < n) {
        if (MODE == 3) {
          const float* Af = (const float*)Ain;
          const float4 f0 = *(const float4*)(Af + (size_t)gr * 128 + (u >> 1));
          const float4 f1 = *(const float4*)(Af + (size_t)gr * 128 + (u >> 1) + 4);
          v.x = pack2(f0.x, f0.y); v.y = pack2(f0.z, f0.w);
          v.z = pack2(f1.x, f1.y); v.w = pack2(f1.z, f1.w);
        } else {
          v = *(const uint4*)((const char*)Ain + (size_t)gr * 256 + u);
          if (MODE == 2) {
            const int c0 = u >> 1;
            unsigned int pw[4] = {v.x, v.y, v.z, v.w};
            #pragma unroll
            for (int p = 0; p < 4; ++p) {
              float lo = b2f_lo(pw[p]);
              float hi = b2f_hi(pw[p]);
              lo = fmaxf(fmaf(lo, scale[c0 + 2 * p], shift[c0 + 2 * p]), 0.f);
              hi = fmaxf(fmaf(hi, scale[c0 + 2 * p + 1], shift[c0 + 2 * p + 1]), 0.f);
              pw[p] = pack2(lo, hi);
            }
            v = make_uint4(pw[0], pw[1], pw[2], pw[3]);
          }
        }
      }
      *(uint4*)(Al + swz(r, u)) = v;
    }
  }
  __syncthreads();

  const int w = t >> 6;
  const int l = t & 63;
  const int lane31 = l & 31;
  const int khalf = l >> 5;
  const int mrow = (w & 1) * 32;
  const int c0 = (w >> 1) * 64;

  f32x16 acc0, acc1;
  #pragma unroll
  for (int i = 0; i < 16; ++i) { acc0[i] = 0.f; acc1[i] = 0.f; }

  #pragma unroll
  for (int k0 = 0; k0 < 128; k0 += 16) {
    const int kb = (k0 + 8 * khalf) * 2;
    const bf16x8 a  = *(const bf16x8*)(Al + swz(mrow + lane31, kb));
    const bf16x8 b0 = *(const bf16x8*)(Wl + swz(c0 + lane31, kb));
    const bf16x8 b1 = *(const bf16x8*)(Wl + swz(c0 + 32 + lane31, kb));
    acc0 = __builtin_amdgcn_mfma_f32_32x32x16_bf16(a, b0, acc0, 0, 0, 0);
    acc1 = __builtin_amdgcn_mfma_f32_32x32x16_bf16(a, b1, acc1, 0, 0, 0);
  }

  const float bias0 = bias[c0 + lane31];
  const float bias1 = bias[c0 + 32 + lane31];
  float s0 = 0.f, q0 = 0.f, s1 = 0.f, q1 = 0.f;
  #pragma unroll
  for (int r = 0; r < 16; ++r) {
    const int row = mrow + (r & 3) + 8 * (r >> 2) + 4 * khalf;
    const int grow = row0 + row;
    if (grow < n) {
      const float v0 = acc0[r] + bias0;
      const float v1 = acc1[r] + bias1;
      C[(size_t)grow * 128 + c0 + lane31] = f2b(v0);
      C[(size_t)grow * 128 + c0 + 32 + lane31] = f2b(v1);
      if (STATS) {
        s0 += v0; q0 = fmaf(v0, v0, q0);
        s1 += v1; q1 = fmaf(v1, v1, q1);
      }
    }
  }
  if (STATS) {
    atomicAdd(&colsum[c0 + lane31], s0);
    atomicAdd(&colsq[c0 + lane31], q0);
    atomicAdd(&colsum[c0 + 32 + lane31], s1);
    atomicAdd(&colsq[c0 + 32 + lane31], q1);
    __syncthreads();
    if (t < 128) {
      const int slot = blockIdx.x & (NSLOT - 1);
      atomicAdd(&psum[slot * 128 + t], colsum[t]);
      atomicAdd(&psq[slot * 128 + t], colsq[t]);
    }
  }
}

// ---------------------------------------------------------------------------
// Weight conversion to bf16 (transposed)
// ---------------------------------------------------------------------------
__global__ __launch_bounds__(256) void conv_w_k(
    const float* __restrict__ lw, const float* __restrict__ w1,
    const float* __restrict__ w2, unsigned short* __restrict__ Wt) {
  const int i = blockIdx.x * 256 + threadIdx.x;
  if (i >= 5 * 16384) return;
  const int m = i >> 14, r = i & 16383;
  const int ncol = r >> 7, k = r & 127;
  const float* src = (m == 0) ? lw : (m <= 2) ? (w1 + (m - 1) * 16384)
                                              : (w2 + (m - 3) * 16384);
  Wt[i] = f2b(src[k * 128 + ncol]);
}

// ---------------------------------------------------------------------------
// CSR build: histogram -> hierarchical scan -> bucket fill (cursor = rowptr)
// ---------------------------------------------------------------------------
#define SCAN_B 196
__global__ __launch_bounds__(256) void edge_hist(const int* __restrict__ ei,
                                                 int* __restrict__ cnt) {
  const int e = blockIdx.x * 256 + threadIdx.x;
  if (e >= NE) return;
  atomicAdd(&cnt[ei[NE + e]], 1);
}

__global__ __launch_bounds__(256) void scan1(const int* __restrict__ cnt,
                                             int* __restrict__ rowptr,
                                             int* __restrict__ bsum) {
  __shared__ int s[256];
  const int b = blockIdx.x, t = threadIdx.x;
  const int i = b * 256 + t;
  const int v = (i < NN) ? cnt[i] : 0;
  s[t] = v;
  __syncthreads();
  for (int off = 1; off < 256; off <<= 1) {
    const int x = (t >= off) ? s[t - off] : 0;
    __syncthreads();
    s[t] += x;
    __syncthreads();
  }
  if (i < NN) rowptr[i] = s[t] - v;
  if (t == 255) bsum[b] = s[255];
}

__global__ __launch_bounds__(256) void scan2(const int* __restrict__ bsum,
                                             int* __restrict__ boff,
                                             int* __restrict__ rowptrN) {
  __shared__ int s[256];
  const int t = threadIdx.x;
  const int v = (t < SCAN_B) ? bsum[t] : 0;
  s[t] = v;
  __syncthreads();
  for (int off = 1; off < 256; off <<= 1) {
    const int x = (t >= off) ? s[t - off] : 0;
    __syncthreads();
    s[t] += x;
    __syncthreads();
  }
  if (t < SCAN_B) boff[t] = s[t] - v;
  if (t == 255) *rowptrN = s[255];
}

__global__ __launch_bounds__(256) void scan3(int* __restrict__ rowptr,
                                             const int* __restrict__ boff,
                                             int* __restrict__ cursor) {
  const int i = blockIdx.x * 256 + threadIdx.x;
  if (i < NN) {
    const int v = rowptr[i] + boff[blockIdx.x];
    rowptr[i] = v;
    cursor[i] = v;
  }
}

__global__ __launch_bounds__(256) void build_csr(const int* __restrict__ ei,
                                                 int* __restrict__ cursor,
                                                 int* __restrict__ srcs) {
  const int e = blockIdx.x * 256 + threadIdx.x;
  if (e >= NE) return;
  const int src = ei[e];
  const int dst = ei[NE + e];
  const int pos = atomicAdd(&cursor[dst], 1);
  srcs[pos] = src;
}

// ---------------------------------------------------------------------------
// BN finalize from 16-slot partials
// ---------------------------------------------------------------------------
__global__ void bn_stats_final(const float* __restrict__ psum,
                               const float* __restrict__ psq,
                               const float* __restrict__ gamma,
                               const float* __restrict__ beta,
                               float* __restrict__ scale,
                               float* __restrict__ shift, int n) {
  const int c = threadIdx.x;  // 128 threads
  float s = 0.f, s2 = 0.f;
  #pragma unroll
  for (int b = 0; b < NSLOT; ++b) {
    s += psum[b * 128 + c];
    s2 += psq[b * 128 + c];
  }
  const float inv_n = 1.f / (float)n;
  const float mu = s * inv_n;
  float var = s2 * inv_n - mu * mu;
  var = fmaxf(var, 0.f);
  const float sc = rsqrtf(var + BN_EPS) * gamma[c];
  scale[c] = sc;
  shift[c] = beta[c] - mu * sc;
}

// ---------------------------------------------------------------------------
// Per-graph fused BN+ReLU+mean-pool accumulate (bf16 in, fp32 pooled out)
// ---------------------------------------------------------------------------
template <bool WRITE_H>
__global__ __launch_bounds__(256) void bn_relu_pool_seg_b(
    const unsigned short* __restrict__ Z, const float* __restrict__ scale,
    const float* __restrict__ shift, const int* __restrict__ gstart,
    unsigned short* __restrict__ h, float* __restrict__ pooled, int layerOff) {
  const int g = blockIdx.x;
  const int r0 = gstart[g], r1 = gstart[g + 1];
  const int t = threadIdx.x;
  const int q = t & 15;
  const int rr = t >> 4;
  const int c0 = q * 8;
  float sc[8], sh[8], acc[8];
  #pragma unroll
  for (int i = 0; i < 8; ++i) { sc[i] = scale[c0 + i]; sh[i] = shift[c0 + i]; acc[i] = 0.f; }
  for (int r = r0 + rr; r < r1; r += 16) {
    const uint4 v = ((const uint4*)Z)[(size_t)r * 16 + q];
    float o[8];
    o[0] = b2f_lo(v.x); o[1] = b2f_hi(v.x); o[2] = b2f_lo(v.y); o[3] = b2f_hi(v.y);
    o[4] = b2f_lo(v.z); o[5] = b2f_hi(v.z); o[6] = b2f_lo(v.w); o[7] = b2f_hi(v.w);
    #pragma unroll
    for (int i = 0; i < 8; ++i) {
      o[i] = fmaxf(fmaf(o[i], sc[i], sh[i]), 0.f);
      acc[i] += o[i];
    }
    if (WRITE_H) {
      uint4 ov;
      ov.x = pack2(o[0], o[1]); ov.y = pack2(o[2], o[3]);
      ov.z = pack2(o[4], o[5]); ov.w = pack2(o[6], o[7]);
      ((uint4*)h)[(size_t)r * 16 + q] = ov;
    }
  }
  __shared__ float red[256 * 8];
  #pragma unroll
  for (int i = 0; i < 8; ++i) red[t * 8 + i] = acc[i];
  __syncthreads();
  for (int off = 8; off >= 1; off >>= 1) {
    if (rr < off) {
      #pragma unroll
      for (int i = 0; i < 8; ++i)
        red[t * 8 + i] += red[(t + off * 16) * 8 + i];
    }
    __syncthreads();
  }
  if (rr == 0) {
    #pragma unroll
    for (int i = 0; i < 8; ++i)
      pooled[(size_t)g * 256 + layerOff + c0 + i] = red[t * 8 + i];
  }
}

// ---------------------------------------------------------------------------
__global__ void compute_segments(const int* __restrict__ batch,
                                 int* __restrict__ gstart,
                                 float* __restrict__ counts) {
  const int g = blockIdx.x * blockDim.x + threadIdx.x;
  if (g > NG) return;
  int lo = 0, hi = NN;
  while (lo < hi) { int m = (lo + hi) >> 1; if (batch[m] < g) lo = m + 1; else hi = m; }
  gstart[g] = lo;
  if (g < NG) {
    int lo1 = lo, hi1 = NN;
    while (lo1 < hi1) { int m = (lo1 + hi1) >> 1; if (batch[m] < g + 1) lo1 = m + 1; else hi1 = m; }
    counts[g] = (float)(lo1 - lo);
  }
}

__global__ __launch_bounds__(256) void final_out(
    const float* __restrict__ pooled, const float* __restrict__ counts,
    const float* __restrict__ jkw, const float* __restrict__ jkb,
    float* __restrict__ out) {
  const int wave = threadIdx.x >> 6;
  const int lane = threadIdx.x & 63;
  const int g = blockIdx.x * 4 + wave;
  if (g >= NG) return;
  const float4 p = ((const float4*)(pooled + (size_t)g * 256))[lane];
  const float4 w = ((const float4*)jkw)[lane];
  float s = p.x * w.x + p.y * w.y + p.z * w.z + p.w * w.w;
  for (int off = 32; off; off >>= 1) s += __shfl_down(s, off, 64);
  if (lane == 0) out[g] = s / fmaxf(counts[g], 1.f) + jkb[0];
}

// ---------------------------------------------------------------------------
extern "C" void kernel_launch(void* const* d_in, const int* in_sizes, int n_in,
                              void* d_out, int out_size, void* d_ws,
                              size_t ws_size, hipStream_t stream) {
  const float* x     = (const float*)d_in[0];
  const int*   ei    = (const int*)d_in[1];
  const int*   batch = (const int*)d_in[2];
  const float* lin_w = (const float*)d_in[3];
  const float* lin_b = (const float*)d_in[4];
  const float* w1    = (const float*)d_in[5];
  const float* b1    = (const float*)d_in[6];
  const float* g1    = (const float*)d_in[7];
  const float* be1   = (const float*)d_in[8];
  const float* w2    = (const float*)d_in[9];
  const float* b2    = (const float*)d_in[10];
  const float* g2    = (const float*)d_in[11];
  const float* be2   = (const float*)d_in[12];
  const float* jkw   = (const float*)d_in[13];
  const float* jkb   = (const float*)d_in[14];
  float* out = (float*)d_out;

  char* base = (char*)d_ws;
  unsigned short* hb  = (unsigned short*)base;                 // NN*128 bf16
  unsigned short* agb = hb + (size_t)NN * 128;                 // NN*128 bf16
  unsigned short* WtA = agb + (size_t)NN * 128;                // 5*16384 bf16
  float* scale  = (float*)(WtA + 5 * 16384);                   // 128
  float* shift  = scale + 128;                                 // 128
  float* pooled = shift + 128;                                 // NG*256
  float* counts = pooled + (size_t)NG * 256;                   // NG
  int* gstart = (int*)(counts + NG);                           // NG+1 (+pad)
  int* rowptr = gstart + NG + 4;                               // NN+1 (+pad)
  int* bsum   = rowptr + NN + 4;                               // 196 (+pad)
  int* boff   = bsum + 200;                                    // 196 (+pad)
  int* srcs   = boff + 200;                                    // NE
  int* cnt    = srcs + NE;                                     // NN   (zeroed)
  float* stats = (float*)(cnt + NN);                           // 4*4096 (zeroed)
  // stats layout: set s (0..3): psum = stats + s*4096, psq = psum + 2048

  // one memset covers cnt + all stat slots (contiguous)
  hipMemsetAsync(cnt, 0, (size_t)NN * sizeof(int) + 4 * 4096 * sizeof(float),
                 stream);
  conv_w_k<<<(5 * 16384 + 255) / 256, 256, 0, stream>>>(lin_w, w1, w2, WtA);
  compute_segments<<<3, 256, 0, stream>>>(batch, gstart, counts);

  // CSR build (by dst)
  edge_hist<<<(NE + 255) / 256, 256, 0, stream>>>(ei, cnt);
  scan1<<<SCAN_B, 256, 0, stream>>>(cnt, rowptr, bsum);
  scan2<<<1, 256, 0, stream>>>(bsum, boff, rowptr + NN);
  scan3<<<SCAN_B, 256, 0, stream>>>(rowptr, boff, cnt);
  build_csr<<<(NE + 255) / 256, 256, 0, stream>>>(ei, cnt, srcs);

  const int gemm_grid = (NN + 63) / 64;  // 782

  // h = x @ lin_w + lin_b  (fp32 input read directly)
  gemm_fused<3, false><<<gemm_grid, 256, 0, stream>>>(
      x, nullptr, nullptr, nullptr, nullptr, WtA, lin_b, hb,
      nullptr, nullptr, NN);

  for (int l = 0; l < NL; ++l) {
    float* st1 = stats + (l * 2 + 0) * 4096;
    float* st2 = stats + (l * 2 + 1) * 4096;
    // z = (gather(h)) @ W1 + b1, with fused column stats
    gemm_fused<1, true><<<gemm_grid, 256, 0, stream>>>(
        hb, nullptr, nullptr, rowptr, srcs, WtA + (1 + l) * 16384,
        b1 + l * 128, agb, st1, st1 + 2048, NN);
    bn_stats_final<<<1, 128, 0, stream>>>(st1, st1 + 2048, g1 + l * 128,
                                          be1 + l * 128, scale, shift, NN);
    // z2 = relu(bn(z)) @ W2 + b2 (in-place), with fused column stats
    gemm_fused<2, true><<<gemm_grid, 256, 0, stream>>>(
        agb, scale, shift, nullptr, nullptr, WtA + (3 + l) * 16384,
        b2 + l * 128, agb, st2, st2 + 2048, NN);
    bn_stats_final<<<1, 128, 0, stream>>>(st2, st2 + 2048, g2 + l * 128,
                                          be2 + l * 128, scale, shift, NN);
    if (l + 1 < NL) {
      bn_relu_pool_seg_b<true><<<NG, 256, 0, stream>>>(
          agb, scale, shift, gstart, hb, pooled, l * 128);
    } else {
      bn_relu_pool_seg_b<false><<<NG, 256, 0, stream>>>(
          agb, scale, shift, gstart, hb, pooled, l * 128);
    }
  }

  final_out<<<NG / 4, 256, 0, stream>>>(pooled, counts, jkw, jkb, out);
}

// Round 6
// 253.014 us; speedup vs baseline: 10.8858x; 1.1925x over previous
//
#include <hip/hip_runtime.h>
#include <cstddef>

#define NN 50000
#define NE 640000
#define NG 512
#define NL 2
#define NSLOT 16
constexpr float BN_EPS = 1e-5f;

typedef __attribute__((ext_vector_type(8))) short bf16x8;
typedef __attribute__((ext_vector_type(16))) float f32x16;

__device__ inline float b2f_lo(unsigned int u) {
  union { unsigned int i; float f; } v; v.i = u << 16; return v.f;
}
__device__ inline float b2f_hi(unsigned int u) {
  union { unsigned int i; float f; } v; v.i = u & 0xffff0000u; return v.f;
}
__device__ inline unsigned short f2b(float f) {
  union { float f; unsigned int i; } v; v.f = f;
  return (unsigned short)((v.i + 0x7fffu + ((v.i >> 16) & 1u)) >> 16);
}
__device__ inline unsigned int pack2(float lo, float hi) {
  return (unsigned int)f2b(lo) | ((unsigned int)f2b(hi) << 16);
}
// swizzled LDS byte offset for [row][256B]; 16B-aligned, bijective per row
__device__ inline int swz(int row, int b) { return row * 256 + (b ^ ((row & 15) << 4)); }

__device__ inline void unpack_add(const uint4 v, float* a) {
  a[0] += b2f_lo(v.x); a[1] += b2f_hi(v.x); a[2] += b2f_lo(v.y); a[3] += b2f_hi(v.y);
  a[4] += b2f_lo(v.z); a[5] += b2f_hi(v.z); a[6] += b2f_lo(v.w); a[7] += b2f_hi(v.w);
}

// ---------------------------------------------------------------------------
// Fused MFMA GEMM: C[n x 128](bf16) = f(A) @ W + bias, optional column stats.
// MODE 1: f = CSR gather-sum of bf16 h (GIN agg incl. self)
// MODE 2: f = relu(A*scale + shift), bf16 A (in-place safe)
// MODE 3: f = A, fp32 A
// 256 thr = 4 waves; 64-row tile; wave w: rows (w&1)*32, cols (w>>1)*64.
// B-fragments read directly from global Wt (16 KB, L1-resident).
// ---------------------------------------------------------------------------
template <int MODE, bool STATS>
__global__ __launch_bounds__(256) void gemm_fused(
    const void* __restrict__ Ain, const float* __restrict__ scale,
    const float* __restrict__ shift, const int* __restrict__ rowptr,
    const int* __restrict__ srcs, const unsigned short* __restrict__ Wt,
    const float* __restrict__ bias, unsigned short* __restrict__ C,
    float* __restrict__ psum, float* __restrict__ psq, int n) {
  __shared__ char Al[16384];
  __shared__ float colsum[128];
  __shared__ float colsq[128];
  const int t = threadIdx.x;
  const int row0 = blockIdx.x * 64;

  if (STATS && t < 128) { colsum[t] = 0.f; colsq[t] = 0.f; }

  // ---- stage A (swizzled), per MODE ----
  if (MODE == 1) {
    const uint4* h4 = (const uint4*)Ain;
    const int ln = t >> 2;        // row 0..63
    const int tq = t & 3;         // chunk group: uint4s tq*4..tq*4+3
    const int gr = row0 + ln;
    float a[4][8];
    #pragma unroll
    for (int i = 0; i < 4; ++i)
      #pragma unroll
      for (int p = 0; p < 8; ++p) a[i][p] = 0.f;
    if (gr < n) {
      {
        const uint4* p = &h4[(size_t)gr * 16 + tq * 4];
        #pragma unroll
        for (int i = 0; i < 4; ++i) unpack_add(p[i], a[i]);
      }
      const int beg = rowptr[gr], end = rowptr[gr + 1];
      int j = beg;
      for (; j + 1 < end; j += 2) {
        const uint4* p0 = &h4[(size_t)srcs[j] * 16 + tq * 4];
        const uint4* p1 = &h4[(size_t)srcs[j + 1] * 16 + tq * 4];
        const uint4 v00 = p0[0], v01 = p0[1], v02 = p0[2], v03 = p0[3];
        const uint4 v10 = p1[0], v11 = p1[1], v12 = p1[2], v13 = p1[3];
        unpack_add(v00, a[0]); unpack_add(v01, a[1]);
        unpack_add(v02, a[2]); unpack_add(v03, a[3]);
        unpack_add(v10, a[0]); unpack_add(v11, a[1]);
        unpack_add(v12, a[2]); unpack_add(v13, a[3]);
      }
      if (j < end) {
        const uint4* p0 = &h4[(size_t)srcs[j] * 16 + tq * 4];
        #pragma unroll
        for (int i = 0; i < 4; ++i) unpack_add(p0[i], a[i]);
      }
    }
    #pragma unroll
    for (int i = 0; i < 4; ++i) {
      uint4 o;
      o.x = pack2(a[i][0], a[i][1]); o.y = pack2(a[i][2], a[i][3]);
      o.z = pack2(a[i][4], a[i][5]); o.w = pack2(a[i][6], a[i][7]);
      *(uint4*)(Al + swz(ln, (tq * 4 + i) * 16)) = o;
    }
  } else {
    #pragma unroll
    for (int ii = 0; ii < 4; ++ii) {
      const int i = t + ii * 256;
      const int r = i >> 4;
      const int u = (i & 15) << 4;
      const int gr = row0 + r;
      uint4 v = make_uint4(0u, 0u, 0u, 0u);
      if (gr < n) {
        if (MODE == 3) {
          const float* Af = (const float*)Ain;
          const float4 f0 = *(const float4*)(Af + (size_t)gr * 128 + (u >> 1));
          const float4 f1 = *(const float4*)(Af + (size_t)gr * 128 + (u >> 1) + 4);
          v.x = pack2(f0.x, f0.y); v.y = pack2(f0.z, f0.w);
          v.z = pack2(f1.x, f1.y); v.w = pack2(f1.z, f1.w);
        } else {
          v = *(const uint4*)((const char*)Ain + (size_t)gr * 256 + u);
          if (MODE == 2) {
            const int c0 = u >> 1;
            unsigned int pw[4] = {v.x, v.y, v.z, v.w};
            #pragma unroll
            for (int p = 0; p < 4; ++p) {
              float lo = b2f_lo(pw[p]);
              float hi = b2f_hi(pw[p]);
              lo = fmaxf(fmaf(lo, scale[c0 + 2 * p], shift[c0 + 2 * p]), 0.f);
              hi = fmaxf(fmaf(hi, scale[c0 + 2 * p + 1], shift[c0 + 2 * p + 1]), 0.f);
              pw[p] = pack2(lo, hi);
            }
            v = make_uint4(pw[0], pw[1], pw[2], pw[3]);
          }
        }
      }
      *(uint4*)(Al + swz(r, u)) = v;
    }
  }
  __syncthreads();

  const int w = t >> 6;
  const int l = t & 63;
  const int lane31 = l & 31;
  const int khalf = l >> 5;
  const int mrow = (w & 1) * 32;
  const int c0 = (w >> 1) * 64;

  f32x16 acc0, acc1;
  #pragma unroll
  for (int i = 0; i < 16; ++i) { acc0[i] = 0.f; acc1[i] = 0.f; }

  const unsigned short* Bp0 = Wt + (size_t)(c0 + lane31) * 128 + 8 * khalf;
  const unsigned short* Bp1 = Wt + (size_t)(c0 + 32 + lane31) * 128 + 8 * khalf;

  #pragma unroll
  for (int k0 = 0; k0 < 128; k0 += 16) {
    const int kb = (k0 + 8 * khalf) * 2;
    const bf16x8 a  = *(const bf16x8*)(Al + swz(mrow + lane31, kb));
    const bf16x8 b0 = *(const bf16x8*)(Bp0 + k0);
    const bf16x8 b1 = *(const bf16x8*)(Bp1 + k0);
    acc0 = __builtin_amdgcn_mfma_f32_32x32x16_bf16(a, b0, acc0, 0, 0, 0);
    acc1 = __builtin_amdgcn_mfma_f32_32x32x16_bf16(a, b1, acc1, 0, 0, 0);
  }

  const float bias0 = bias[c0 + lane31];
  const float bias1 = bias[c0 + 32 + lane31];
  float s0 = 0.f, q0 = 0.f, s1 = 0.f, q1 = 0.f;
  #pragma unroll
  for (int r = 0; r < 16; ++r) {
    const int row = mrow + (r & 3) + 8 * (r >> 2) + 4 * khalf;
    const int grow = row0 + row;
    if (grow < n) {
      const float v0 = acc0[r] + bias0;
      const float v1 = acc1[r] + bias1;
      C[(size_t)grow * 128 + c0 + lane31] = f2b(v0);
      C[(size_t)grow * 128 + c0 + 32 + lane31] = f2b(v1);
      if (STATS) {
        s0 += v0; q0 = fmaf(v0, v0, q0);
        s1 += v1; q1 = fmaf(v1, v1, q1);
      }
    }
  }
  if (STATS) {
    atomicAdd(&colsum[c0 + lane31], s0);
    atomicAdd(&colsq[c0 + lane31], q0);
    atomicAdd(&colsum[c0 + 32 + lane31], s1);
    atomicAdd(&colsq[c0 + 32 + lane31], q1);
    __syncthreads();
    if (t < 128) {
      const int slot = blockIdx.x & (NSLOT - 1);
      atomicAdd(&psum[slot * 128 + t], colsum[t]);
      atomicAdd(&psq[slot * 128 + t], colsq[t]);
    }
  }
}

// ---------------------------------------------------------------------------
// Weight conversion to bf16 (transposed)
// ---------------------------------------------------------------------------
__global__ __launch_bounds__(256) void conv_w_k(
    const float* __restrict__ lw, const float* __restrict__ w1,
    const float* __restrict__ w2, unsigned short* __restrict__ Wt) {
  const int i = blockIdx.x * 256 + threadIdx.x;
  if (i >= 5 * 16384) return;
  const int m = i >> 14, r = i & 16383;
  const int ncol = r >> 7, k = r & 127;
  const float* src = (m == 0) ? lw : (m <= 2) ? (w1 + (m - 1) * 16384)
                                              : (w2 + (m - 3) * 16384);
  Wt[i] = f2b(src[k * 128 + ncol]);
}

// ---------------------------------------------------------------------------
// CSR build: histogram -> hierarchical scan -> bucket fill (cursor = rowptr)
// ---------------------------------------------------------------------------
#define SCAN_B 196
__global__ __launch_bounds__(256) void edge_hist(const int* __restrict__ ei,
                                                 int* __restrict__ cnt) {
  const int e = blockIdx.x * 256 + threadIdx.x;
  if (e >= NE) return;
  atomicAdd(&cnt[ei[NE + e]], 1);
}

__global__ __launch_bounds__(256) void scan1(const int* __restrict__ cnt,
                                             int* __restrict__ rowptr,
                                             int* __restrict__ bsum) {
  __shared__ int s[256];
  const int b = blockIdx.x, t = threadIdx.x;
  const int i = b * 256 + t;
  const int v = (i < NN) ? cnt[i] : 0;
  s[t] = v;
  __syncthreads();
  for (int off = 1; off < 256; off <<= 1) {
    const int x = (t >= off) ? s[t - off] : 0;
    __syncthreads();
    s[t] += x;
    __syncthreads();
  }
  if (i < NN) rowptr[i] = s[t] - v;
  if (t == 255) bsum[b] = s[255];
}

__global__ __launch_bounds__(256) void scan2(const int* __restrict__ bsum,
                                             int* __restrict__ boff,
                                             int* __restrict__ rowptrN) {
  __shared__ int s[256];
  const int t = threadIdx.x;
  const int v = (t < SCAN_B) ? bsum[t] : 0;
  s[t] = v;
  __syncthreads();
  for (int off = 1; off < 256; off <<= 1) {
    const int x = (t >= off) ? s[t - off] : 0;
    __syncthreads();
    s[t] += x;
    __syncthreads();
  }
  if (t < SCAN_B) boff[t] = s[t] - v;
  if (t == 255) *rowptrN = s[255];
}

__global__ __launch_bounds__(256) void scan3(int* __restrict__ rowptr,
                                             const int* __restrict__ boff,
                                             int* __restrict__ cursor) {
  const int i = blockIdx.x * 256 + threadIdx.x;
  if (i < NN) {
    const int v = rowptr[i] + boff[blockIdx.x];
    rowptr[i] = v;
    cursor[i] = v;
  }
}

__global__ __launch_bounds__(256) void build_csr(const int* __restrict__ ei,
                                                 int* __restrict__ cursor,
                                                 int* __restrict__ srcs) {
  const int e = blockIdx.x * 256 + threadIdx.x;
  if (e >= NE) return;
  const int src = ei[e];
  const int dst = ei[NE + e];
  const int pos = atomicAdd(&cursor[dst], 1);
  srcs[pos] = src;
}

// ---------------------------------------------------------------------------
// BN finalize from 16-slot partials
// ---------------------------------------------------------------------------
__global__ void bn_stats_final(const float* __restrict__ psum,
                               const float* __restrict__ psq,
                               const float* __restrict__ gamma,
                               const float* __restrict__ beta,
                               float* __restrict__ scale,
                               float* __restrict__ shift, int n) {
  const int c = threadIdx.x;  // 128 threads
  float s = 0.f, s2 = 0.f;
  #pragma unroll
  for (int b = 0; b < NSLOT; ++b) {
    s += psum[b * 128 + c];
    s2 += psq[b * 128 + c];
  }
  const float inv_n = 1.f / (float)n;
  const float mu = s * inv_n;
  float var = s2 * inv_n - mu * mu;
  var = fmaxf(var, 0.f);
  const float sc = rsqrtf(var + BN_EPS) * gamma[c];
  scale[c] = sc;
  shift[c] = beta[c] - mu * sc;
}

// ---------------------------------------------------------------------------
// Per-graph fused BN+ReLU+mean-pool accumulate (bf16 in, fp32 pooled out)
// ---------------------------------------------------------------------------
template <bool WRITE_H>
__global__ __launch_bounds__(256) void bn_relu_pool_seg_b(
    const unsigned short* __restrict__ Z, const float* __restrict__ scale,
    const float* __restrict__ shift, const int* __restrict__ gstart,
    unsigned short* __restrict__ h, float* __restrict__ pooled, int layerOff) {
  const int g = blockIdx.x;
  const int r0 = gstart[g], r1 = gstart[g + 1];
  const int t = threadIdx.x;
  const int q = t & 15;
  const int rr = t >> 4;
  const int c0 = q * 8;
  float sc[8], sh[8], acc[8];
  #pragma unroll
  for (int i = 0; i < 8; ++i) { sc[i] = scale[c0 + i]; sh[i] = shift[c0 + i]; acc[i] = 0.f; }
  for (int r = r0 + rr; r < r1; r += 16) {
    const uint4 v = ((const uint4*)Z)[(size_t)r * 16 + q];
    float o[8];
    o[0] = b2f_lo(v.x); o[1] = b2f_hi(v.x); o[2] = b2f_lo(v.y); o[3] = b2f_hi(v.y);
    o[4] = b2f_lo(v.z); o[5] = b2f_hi(v.z); o[6] = b2f_lo(v.w); o[7] = b2f_hi(v.w);
    #pragma unroll
    for (int i = 0; i < 8; ++i) {
      o[i] = fmaxf(fmaf(o[i], sc[i], sh[i]), 0.f);
      acc[i] += o[i];
    }
    if (WRITE_H) {
      uint4 ov;
      ov.x = pack2(o[0], o[1]); ov.y = pack2(o[2], o[3]);
      ov.z = pack2(o[4], o[5]); ov.w = pack2(o[6], o[7]);
      ((uint4*)h)[(size_t)r * 16 + q] = ov;
    }
  }
  __shared__ float red[256 * 8];
  #pragma unroll
  for (int i = 0; i < 8; ++i) red[t * 8 + i] = acc[i];
  __syncthreads();
  for (int off = 8; off >= 1; off >>= 1) {
    if (rr < off) {
      #pragma unroll
      for (int i = 0; i < 8; ++i)
        red[t * 8 + i] += red[(t + off * 16) * 8 + i];
    }
    __syncthreads();
  }
  if (rr == 0) {
    #pragma unroll
    for (int i = 0; i < 8; ++i)
      pooled[(size_t)g * 256 + layerOff + c0 + i] = red[t * 8 + i];
  }
}

// ---------------------------------------------------------------------------
__global__ void compute_segments(const int* __restrict__ batch,
                                 int* __restrict__ gstart,
                                 float* __restrict__ counts) {
  const int g = blockIdx.x * blockDim.x + threadIdx.x;
  if (g > NG) return;
  int lo = 0, hi = NN;
  while (lo < hi) { int m = (lo + hi) >> 1; if (batch[m] < g) lo = m + 1; else hi = m; }
  gstart[g] = lo;
  if (g < NG) {
    int lo1 = lo, hi1 = NN;
    while (lo1 < hi1) { int m = (lo1 + hi1) >> 1; if (batch[m] < g + 1) lo1 = m + 1; else hi1 = m; }
    counts[g] = (float)(lo1 - lo);
  }
}

__global__ __launch_bounds__(256) void final_out(
    const float* __restrict__ pooled, const float* __restrict__ counts,
    const float* __restrict__ jkw, const float* __restrict__ jkb,
    float* __restrict__ out) {
  const int wave = threadIdx.x >> 6;
  const int lane = threadIdx.x & 63;
  const int g = blockIdx.x * 4 + wave;
  if (g >= NG) return;
  const float4 p = ((const float4*)(pooled + (size_t)g * 256))[lane];
  const float4 w = ((const float4*)jkw)[lane];
  float s = p.x * w.x + p.y * w.y + p.z * w.z + p.w * w.w;
  for (int off = 32; off; off >>= 1) s += __shfl_down(s, off, 64);
  if (lane == 0) out[g] = s / fmaxf(counts[g], 1.f) + jkb[0];
}

// ---------------------------------------------------------------------------
extern "C" void kernel_launch(void* const* d_in, const int* in_sizes, int n_in,
                              void* d_out, int out_size, void* d_ws,
                              size_t ws_size, hipStream_t stream) {
  const float* x     = (const float*)d_in[0];
  const int*   ei    = (const int*)d_in[1];
  const int*   batch = (const int*)d_in[2];
  const float* lin_w = (const float*)d_in[3];
  const float* lin_b = (const float*)d_in[4];
  const float* w1    = (const float*)d_in[5];
  const float* b1    = (const float*)d_in[6];
  const float* g1    = (const float*)d_in[7];
  const float* be1   = (const float*)d_in[8];
  const float* w2    = (const float*)d_in[9];
  const float* b2    = (const float*)d_in[10];
  const float* g2    = (const float*)d_in[11];
  const float* be2   = (const float*)d_in[12];
  const float* jkw   = (const float*)d_in[13];
  const float* jkb   = (const float*)d_in[14];
  float* out = (float*)d_out;

  char* base = (char*)d_ws;
  unsigned short* hb  = (unsigned short*)base;                 // NN*128 bf16
  unsigned short* agb = hb + (size_t)NN * 128;                 // NN*128 bf16
  unsigned short* WtA = agb + (size_t)NN * 128;                // 5*16384 bf16
  float* scale  = (float*)(WtA + 5 * 16384);                   // 128
  float* shift  = scale + 128;                                 // 128
  float* pooled = shift + 128;                                 // NG*256
  float* counts = pooled + (size_t)NG * 256;                   // NG
  int* gstart = (int*)(counts + NG);                           // NG+1 (+pad)
  int* rowptr = gstart + NG + 4;                               // NN+1 (+pad)
  int* bsum   = rowptr + NN + 4;                               // 196 (+pad)
  int* boff   = bsum + 200;                                    // 196 (+pad)
  int* srcs   = boff + 200;                                    // NE
  int* cnt    = srcs + NE;                                     // NN   (zeroed)
  float* stats = (float*)(cnt + NN);                           // 4*4096 (zeroed)
  // stats layout: set s (0..3): psum = stats + s*4096, psq = psum + 2048

  // one memset covers cnt + all stat slots (contiguous)
  hipMemsetAsync(cnt, 0, (size_t)NN * sizeof(int) + 4 * 4096 * sizeof(float),
                 stream);
  conv_w_k<<<(5 * 16384 + 255) / 256, 256, 0, stream>>>(lin_w, w1, w2, WtA);
  compute_segments<<<3, 256, 0, stream>>>(batch, gstart, counts);

  // CSR build (by dst)
  edge_hist<<<(NE + 255) / 256, 256, 0, stream>>>(ei, cnt);
  scan1<<<SCAN_B, 256, 0, stream>>>(cnt, rowptr, bsum);
  scan2<<<1, 256, 0, stream>>>(bsum, boff, rowptr + NN);
  scan3<<<SCAN_B, 256, 0, stream>>>(rowptr, boff, cnt);
  build_csr<<<(NE + 255) / 256, 256, 0, stream>>>(ei, cnt, srcs);

  const int gemm_grid = (NN + 63) / 64;  // 782

  // h = x @ lin_w + lin_b  (fp32 input read directly)
  gemm_fused<3, false><<<gemm_grid, 256, 0, stream>>>(
      x, nullptr, nullptr, nullptr, nullptr, WtA, lin_b, hb,
      nullptr, nullptr, NN);

  for (int l = 0; l < NL; ++l) {
    float* st1 = stats + (l * 2 + 0) * 4096;
    float* st2 = stats + (l * 2 + 1) * 4096;
    // z = (gather(h)) @ W1 + b1, with fused column stats
    gemm_fused<1, true><<<gemm_grid, 256, 0, stream>>>(
        hb, nullptr, nullptr, rowptr, srcs, WtA + (1 + l) * 16384,
        b1 + l * 128, agb, st1, st1 + 2048, NN);
    bn_stats_final<<<1, 128, 0, stream>>>(st1, st1 + 2048, g1 + l * 128,
                                          be1 + l * 128, scale, shift, NN);
    // z2 = relu(bn(z)) @ W2 + b2 (in-place), with fused column stats
    gemm_fused<2, true><<<gemm_grid, 256, 0, stream>>>(
        agb, scale, shift, nullptr, nullptr, WtA + (3 + l) * 16384,
        b2 + l * 128, agb, st2, st2 + 2048, NN);
    bn_stats_final<<<1, 128, 0, stream>>>(st2, st2 + 2048, g2 + l * 128,
                                          be2 + l * 128, scale, shift, NN);
    if (l + 1 < NL) {
      bn_relu_pool_seg_b<true><<<NG, 256, 0, stream>>>(
          agb, scale, shift, gstart, hb, pooled, l * 128);
    } else {
      bn_relu_pool_seg_b<false><<<NG, 256, 0, stream>>>(
          agb, scale, shift, gstart, hb, pooled, l * 128);
    }
  }

  final_out<<<NG / 4, 256, 0, stream>>>(pooled, counts, jkw, jkb, out);
}